// Round 2
// baseline (4470.643 us; speedup 1.0000x reference)
//
#include <hip/hip_runtime.h>
#include <hip/hip_bf16.h>
#include <cstddef>

// Problem constants
#define BATCH 2
#define CCH   128        // C
#define HS    32         // H = W = T
#define LSP   32768      // 32^3 spatial per batch
#define TOK   65536      // BATCH * LSP  (== windowed token count)
#define NWIN  512        // windows per batch (8^3)
#define HEADS 8
#define HD    16
#define MLPD  512
#define OUTC  256
#define CH    16384      // tokens per chunk (1/4 of TOK); never straddles batch

// ---------------------------------------------------------------------------
// Transpose input (B,C,32,32,32) -> token-major xbuf[(b*32768+sp)*128 + c]
// ---------------------------------------------------------------------------
__global__ __launch_bounds__(256) void transpose_in_kernel(
    const float* __restrict__ x, float* __restrict__ out)
{
    __shared__ float tile[128 * 65];
    int chunk = blockIdx.x;            // 1024 blocks: 512 per batch, 64 sp each
    int tid = threadIdx.x;
    int b = chunk >> 9;
    int sp0 = (chunk & 511) * 64;
    #pragma unroll
    for (int l = 0; l < 32; ++l) {
        int idx = l * 256 + tid;
        int c = idx >> 6;              // 0..127
        int s = idx & 63;              // 0..63
        tile[c * 65 + s] = x[(((size_t)(b * 128 + c)) << 15) + sp0 + s];
    }
    __syncthreads();
    #pragma unroll
    for (int l = 0; l < 32; ++l) {
        int idx = l * 256 + tid;
        int s = idx >> 7;              // 0..63
        int c = idx & 127;             // 0..127
        out[((size_t)((b << 15) + sp0 + s)) * 128 + c] = tile[c * 65 + s];
    }
}

// ---------------------------------------------------------------------------
// LayerNorm + cyclic shift + window partition (gather), chunk of CH tokens.
// grid = CH, block = 64. m0 = global windowed-token base of chunk.
// ---------------------------------------------------------------------------
__global__ __launch_bounds__(64) void ln_window_kernel(
    const float* __restrict__ x, float* __restrict__ out,
    const float* __restrict__ g, const float* __restrict__ bta, int shift, int m0)
{
    int m = m0 + blockIdx.x;           // global windowed token
    int tid = threadIdx.x;
    int n = m & 63, w = (m >> 6) & 511, b = m >> 15;
    int ih = n >> 4, iw = (n >> 2) & 3, it = n & 3;
    int wh = w >> 6, ww = (w >> 3) & 7, wt = w & 7;
    int h  = (wh * 4 + ih + shift) & 31;
    int w2 = (ww * 4 + iw + shift) & 31;
    int t  = (wt * 4 + it + shift) & 31;
    size_t tok = ((size_t)b << 15) + ((h * 32 + w2) * 32 + t);
    const float* xp = x + tok * 128;
    float v0 = xp[tid], v1 = xp[tid + 64];
    float s = v0 + v1, sq = v0 * v0 + v1 * v1;
    #pragma unroll
    for (int o = 32; o > 0; o >>= 1) { s += __shfl_xor(s, o); sq += __shfl_xor(sq, o); }
    float mu  = s * (1.0f / 128.0f);
    float var = sq * (1.0f / 128.0f) - mu * mu;
    float rs  = rsqrtf(var + 1e-5f);
    float* op = out + (size_t)blockIdx.x * 128;
    op[tid]      = (v0 - mu) * rs * g[tid]      + bta[tid];
    op[tid + 64] = (v1 - mu) * rs * g[tid + 64] + bta[tid + 64];
}

// Plain LayerNorm chunk (x pre-offset to chunk). grid = CH, block = 64
__global__ __launch_bounds__(64) void ln_plain_kernel(
    const float* __restrict__ x, float* __restrict__ out,
    const float* __restrict__ g, const float* __restrict__ bta)
{
    size_t tok = blockIdx.x;
    int tid = threadIdx.x;
    const float* xp = x + tok * 128;
    float v0 = xp[tid], v1 = xp[tid + 64];
    float s = v0 + v1, sq = v0 * v0 + v1 * v1;
    #pragma unroll
    for (int o = 32; o > 0; o >>= 1) { s += __shfl_xor(s, o); sq += __shfl_xor(sq, o); }
    float mu  = s * (1.0f / 128.0f);
    float var = sq * (1.0f / 128.0f) - mu * mu;
    float rs  = rsqrtf(var + 1e-5f);
    float* op = out + tok * 128;
    op[tid]      = (v0 - mu) * rs * g[tid]      + bta[tid];
    op[tid + 64] = (v1 - mu) * rs * g[tid + 64] + bta[tid + 64];
}

// ---------------------------------------------------------------------------
// Generic fp32 tiled GEMM: V[M,N] = A[M,K] @ B[N,K]^T + bias, with epilogues.
// 64x64 tile, BK=16, 256 threads, 4x4 per thread. M,N mult of 64, K mult of 16.
// mode 0: C[m*N+n] = v
// mode 1: C[m*N+n] = gelu(v)
// mode 2: scatter-add (un-shift window) into aux (=xbuf): aux[tok*128+n] += v
// mode 3: aux[(m0+m)*128+n] += v          (plain residual)
// mode 4: per-channel stats: aux[n] += v, aux[256+n] += v*v  (atomics, no store)
// mode 5: BN+ReLU+transpose: C = d_out, aux = stats, p1 = bn_g, p2 = bn_b
// ---------------------------------------------------------------------------
__global__ __launch_bounds__(256) void gemm_kernel(
    const float* __restrict__ A, const float* __restrict__ Bw,
    const float* __restrict__ bias, float* __restrict__ C,
    float* __restrict__ aux, const float* __restrict__ p1, const float* __restrict__ p2,
    int M, int N, int K, int mode, int m0, int shift)
{
    __shared__ float As[16][64];
    __shared__ float Bs[16][64];
    __shared__ float cs[64];
    __shared__ float cq[64];
    int tid = threadIdx.x;
    int tx = tid & 15, ty = tid >> 4;
    int nBase = blockIdx.x * 64;
    int mBase = blockIdx.y * 64;
    float acc[4][4] = {};
    for (int k0 = 0; k0 < K; k0 += 16) {
        #pragma unroll
        for (int l = 0; l < 4; ++l) {
            int idx = l * 256 + tid;
            int r = idx >> 4;
            int kk = idx & 15;
            As[kk][r] = A[(size_t)(mBase + r) * K + k0 + kk];
            Bs[kk][r] = Bw[(size_t)(nBase + r) * K + k0 + kk];
        }
        __syncthreads();
        #pragma unroll
        for (int kk = 0; kk < 16; ++kk) {
            float4 a = *(const float4*)&As[kk][ty * 4];
            float4 b = *(const float4*)&Bs[kk][tx * 4];
            float av[4] = {a.x, a.y, a.z, a.w};
            float bv[4] = {b.x, b.y, b.z, b.w};
            #pragma unroll
            for (int i = 0; i < 4; ++i)
                #pragma unroll
                for (int j = 0; j < 4; ++j)
                    acc[i][j] += av[i] * bv[j];
        }
        __syncthreads();
    }

    if (mode == 4) {
        if (tid < 64) { cs[tid] = 0.f; cq[tid] = 0.f; }
        __syncthreads();
        #pragma unroll
        for (int i = 0; i < 4; ++i) {
            #pragma unroll
            for (int j = 0; j < 4; ++j) {
                float v = acc[i][j] + bias[nBase + tx * 4 + j];
                atomicAdd(&cs[tx * 4 + j], v);
                atomicAdd(&cq[tx * 4 + j], v * v);
            }
        }
        __syncthreads();
        if (tid < 64) {
            atomicAdd(&aux[nBase + tid], cs[tid]);
            atomicAdd(&aux[256 + nBase + tid], cq[tid]);
        }
        return;
    }

    #pragma unroll
    for (int i = 0; i < 4; ++i) {
        int m = mBase + ty * 4 + i;
        #pragma unroll
        for (int j = 0; j < 4; ++j) {
            int nn = nBase + tx * 4 + j;
            float v = acc[i][j] + bias[nn];
            if (mode == 0) {
                C[(size_t)m * N + nn] = v;
            } else if (mode == 1) {
                C[(size_t)m * N + nn] = 0.5f * v * (1.0f + erff(v * 0.70710678118654752f));
            } else if (mode == 2) {
                int g = m0 + m;
                int n_ = g & 63, w = (g >> 6) & 511, b = g >> 15;
                int ih = n_ >> 4, iw = (n_ >> 2) & 3, it = n_ & 3;
                int wh = w >> 6, ww = (w >> 3) & 7, wt = w & 7;
                int h  = (wh * 4 + ih + shift) & 31;
                int w2 = (ww * 4 + iw + shift) & 31;
                int t  = (wt * 4 + it + shift) & 31;
                size_t tok = ((size_t)b << 15) + ((h * 32 + w2) * 32 + t);
                aux[tok * 128 + nn] += v;
            } else if (mode == 3) {
                aux[(size_t)(m0 + m) * 128 + nn] += v;
            } else { // mode 5
                int g = m0 + m;
                int b = g >> 15, sp = g & 32767;
                float mean = aux[nn] * (1.0f / 65536.0f);
                float var  = aux[256 + nn] * (1.0f / 65536.0f) - mean * mean;
                float y = (v - mean) * rsqrtf(var + 1e-5f) * p1[nn] + p2[nn];
                C[(((size_t)(b * 256 + nn)) << 15) + sp] = fmaxf(y, 0.f);
            }
        }
    }
}

// ---------------------------------------------------------------------------
// Windowed attention: one block per (window-in-chunk, head); 64 threads.
// qkv chunk-local [CH,384]; wBase = global window base of chunk.
// ---------------------------------------------------------------------------
__global__ __launch_bounds__(64) void attn_kernel(
    const float* __restrict__ qkv, const float* __restrict__ rpb,
    float* __restrict__ outp, int shift, int wBase)
{
    __shared__ float kt[64][16];
    __shared__ float vt[64][16];
    __shared__ float rp[343];
    __shared__ int   cnt[64];
    int blk = blockIdx.x;
    int head = blk & 7;
    int lw = blk >> 3;                 // local window in chunk (0..255)
    int i = threadIdx.x;
    const float* base = qkv + (size_t)(lw * 64) * 384 + head * 16;
    float q[16];
    #pragma unroll
    for (int d = 0; d < 16; ++d) q[d] = base[(size_t)i * 384 + d] * 0.25f;
    #pragma unroll
    for (int d = 0; d < 16; ++d) kt[i][d] = base[(size_t)i * 384 + 128 + d];
    #pragma unroll
    for (int d = 0; d < 16; ++d) vt[i][d] = base[(size_t)i * 384 + 256 + d];
    for (int j = i; j < 343; j += 64) rp[j] = rpb[(size_t)j * 8 + head];
    int w = (wBase + lw) & 511;        // window within batch
    int ih = i >> 4, iw = (i >> 2) & 3, it = i & 3;
    if (shift) {
        int wh = w >> 6, ww = (w >> 3) & 7, wt = w & 7;
        int h = wh * 4 + ih, w2 = ww * 4 + iw, t = wt * 4 + it;
        int rh = (h  < 28) ? 0 : ((h  < 30) ? 1 : 2);
        int rw = (w2 < 28) ? 0 : ((w2 < 30) ? 1 : 2);
        int rt = (t  < 28) ? 0 : ((t  < 30) ? 1 : 2);
        cnt[i] = (rh * 3 + rw) * 3 + rt;
    }
    __syncthreads();
    float logits[64];
    int ci = shift ? cnt[i] : 0;
    #pragma unroll
    for (int j = 0; j < 64; ++j) {
        float d0 = 0.f;
        #pragma unroll
        for (int d = 0; d < 16; ++d) d0 += q[d] * kt[j][d];
        int jh = j >> 4, jw = (j >> 2) & 3, jt = j & 3;
        int ridx = ((ih - jh + 3) * 7 + (iw - jw + 3)) * 7 + (it - jt + 3);
        d0 += rp[ridx];
        if (shift && cnt[j] != ci) d0 -= 100.0f;
        logits[j] = d0;
    }
    float mx = -1e30f;
    #pragma unroll
    for (int j = 0; j < 64; ++j) mx = fmaxf(mx, logits[j]);
    float ssum = 0.f;
    #pragma unroll
    for (int j = 0; j < 64; ++j) { float e = __expf(logits[j] - mx); logits[j] = e; ssum += e; }
    float inv = 1.0f / ssum;
    float o[16] = {};
    #pragma unroll
    for (int j = 0; j < 64; ++j) {
        float p = logits[j] * inv;
        #pragma unroll
        for (int d = 0; d < 16; ++d) o[d] += p * vt[j][d];
    }
    float* op = outp + (size_t)(lw * 64 + i) * 128 + head * 16;
    #pragma unroll
    for (int d = 0; d < 16; ++d) op[d] = o[d];
}

// ---------------------------------------------------------------------------
// Depthwise 3x3x3 conv chunk, SAME zero-pad. grid = CH, block = 128.
// Reads full xbuf (token-major); writes chunk-local out.
// ---------------------------------------------------------------------------
__global__ __launch_bounds__(128) void dwconv_kernel(
    const float* __restrict__ x, const float* __restrict__ wgt,
    const float* __restrict__ bias, float* __restrict__ out, int t0)
{
    int tokl = blockIdx.x;
    int tok = t0 + tokl;
    int c = threadIdx.x;
    int sp = tok & 32767, b = tok >> 15;
    int t = sp & 31, w = (sp >> 5) & 31, h = sp >> 10;
    float acc = bias[c];
    #pragma unroll
    for (int kh = -1; kh <= 1; ++kh) {
        int hh = h + kh; if (hh < 0 || hh > 31) continue;
        #pragma unroll
        for (int kw = -1; kw <= 1; ++kw) {
            int ww = w + kw; if (ww < 0 || ww > 31) continue;
            #pragma unroll
            for (int kt = -1; kt <= 1; ++kt) {
                int tt = t + kt; if (tt < 0 || tt > 31) continue;
                size_t ntok = ((size_t)b << 15) + ((hh * 32 + ww) * 32 + tt);
                acc += x[ntok * 128 + c] * wgt[c * 27 + ((kh + 1) * 3 + (kw + 1)) * 3 + (kt + 1)];
            }
        }
    }
    out[(size_t)tokl * 128 + c] = acc;
}

__global__ void zero_kernel(float* __restrict__ p, int n)
{
    int i = blockIdx.x * blockDim.x + threadIdx.x;
    if (i < n) p[i] = 0.f;
}

// ---------------------------------------------------------------------------
extern "C" void kernel_launch(void* const* d_in, const int* in_sizes, int n_in,
                              void* d_out, int out_size, void* d_ws, size_t ws_size,
                              hipStream_t stream)
{
    const float* x_in    = (const float*)d_in[0];
    const float* norm1_g = (const float*)d_in[1];
    const float* norm1_b = (const float*)d_in[2];
    const float* qkv_w   = (const float*)d_in[3];
    const float* qkv_b   = (const float*)d_in[4];
    const float* proj_w  = (const float*)d_in[5];
    const float* proj_b  = (const float*)d_in[6];
    const float* rpb     = (const float*)d_in[7];
    const float* norm2_g = (const float*)d_in[8];
    const float* norm2_b = (const float*)d_in[9];
    const float* fc1_w   = (const float*)d_in[10];
    const float* fc1_b   = (const float*)d_in[11];
    const float* fc2_w   = (const float*)d_in[12];
    const float* fc2_b   = (const float*)d_in[13];
    const float* dw_w    = (const float*)d_in[14];
    const float* dw_b    = (const float*)d_in[15];
    const float* pw_w    = (const float*)d_in[16];
    const float* pw_b    = (const float*)d_in[17];
    const float* bn_g    = (const float*)d_in[18];
    const float* bn_b    = (const float*)d_in[19];
    float* out = (float*)d_out;

    // Workspace layout — total 72 MB + 2 KB (well under any plausible ws_size)
    char* ws = (char*)d_ws;
    float* xbuf    = (float*)(ws);                              // 32 MB [TOK,128]
    char*  S       = ws + 33554432ULL;
    float* lnbuf   = (float*)(S);                               // 8 MB  [CH,128] (also dwbuf)
    float* qkvbuf  = (float*)(S + 8388608ULL);                  // 24 MB [CH,384]
    float* attnbuf = (float*)(S + 33554432ULL);                 // 8 MB  [CH,128]
    float* hidbuf  = (float*)(S + 8388608ULL);                  // 32 MB [CH,512] (overlaps qkv+attn, different phase)
    float* stats   = (float*)(S + 41943040ULL);                 // 2 KB  [512]

    // 1) transpose input to token-major
    hipLaunchKernelGGL(transpose_in_kernel, dim3(1024), dim3(256), 0, stream, x_in, xbuf);

    const int shifts[4] = {0, 2, 0, 2};
    for (int i = 0; i < 4; ++i) {
        int s = shifts[i];
        // --- attention half, chunked by windows (256 windows / 16384 tokens) ---
        for (int c0 = 0; c0 < 4; ++c0) {
            int m0 = c0 * CH;
            hipLaunchKernelGGL(ln_window_kernel, dim3(CH), dim3(64), 0, stream,
                               xbuf, lnbuf, norm1_g + i * 128, norm1_b + i * 128, s, m0);
            hipLaunchKernelGGL(gemm_kernel, dim3(384 / 64, CH / 64), dim3(256), 0, stream,
                               lnbuf, qkv_w + (size_t)i * 384 * 128, qkv_b + i * 384,
                               qkvbuf, (float*)nullptr, (const float*)nullptr, (const float*)nullptr,
                               CH, 384, 128, 0, 0, 0);
            hipLaunchKernelGGL(attn_kernel, dim3(256 * HEADS), dim3(64), 0, stream,
                               qkvbuf, rpb + (size_t)i * 343 * 8, attnbuf, s, m0 / 64);
            hipLaunchKernelGGL(gemm_kernel, dim3(128 / 64, CH / 64), dim3(256), 0, stream,
                               attnbuf, proj_w + (size_t)i * 128 * 128, proj_b + i * 128,
                               (float*)nullptr, xbuf, (const float*)nullptr, (const float*)nullptr,
                               CH, 128, 128, 2, m0, s);
        }
        // --- MLP half, chunked by tokens ---
        for (int c0 = 0; c0 < 4; ++c0) {
            int m0 = c0 * CH;
            hipLaunchKernelGGL(ln_plain_kernel, dim3(CH), dim3(64), 0, stream,
                               xbuf + (size_t)m0 * 128, lnbuf, norm2_g + i * 128, norm2_b + i * 128);
            hipLaunchKernelGGL(gemm_kernel, dim3(512 / 64, CH / 64), dim3(256), 0, stream,
                               lnbuf, fc1_w + (size_t)i * 512 * 128, fc1_b + i * 512,
                               hidbuf, (float*)nullptr, (const float*)nullptr, (const float*)nullptr,
                               CH, 512, 128, 1, 0, 0);
            hipLaunchKernelGGL(gemm_kernel, dim3(128 / 64, CH / 64), dim3(256), 0, stream,
                               hidbuf, fc2_w + (size_t)i * 128 * 512, fc2_b + i * 128,
                               (float*)nullptr, xbuf, (const float*)nullptr, (const float*)nullptr,
                               CH, 128, 512, 3, m0, 0);
        }
    }

    // connectBlock: two-pass BN (stats pass, then recompute + normalize)
    hipLaunchKernelGGL(zero_kernel, dim3(2), dim3(256), 0, stream, stats, 512);
    for (int c0 = 0; c0 < 4; ++c0) {
        int t0 = c0 * CH;
        hipLaunchKernelGGL(dwconv_kernel, dim3(CH), dim3(128), 0, stream,
                           xbuf, dw_w, dw_b, lnbuf, t0);
        hipLaunchKernelGGL(gemm_kernel, dim3(OUTC / 64, CH / 64), dim3(256), 0, stream,
                           lnbuf, pw_w, pw_b,
                           (float*)nullptr, stats, (const float*)nullptr, (const float*)nullptr,
                           CH, OUTC, 128, 4, 0, 0);
    }
    for (int c0 = 0; c0 < 4; ++c0) {
        int t0 = c0 * CH;
        hipLaunchKernelGGL(dwconv_kernel, dim3(CH), dim3(128), 0, stream,
                           xbuf, dw_w, dw_b, lnbuf, t0);
        hipLaunchKernelGGL(gemm_kernel, dim3(OUTC / 64, CH / 64), dim3(256), 0, stream,
                           lnbuf, pw_w, pw_b,
                           out, stats, bn_g, bn_b,
                           CH, OUTC, 128, 5, t0, 0);
    }
}

// Round 3
// 1868.943 us; speedup vs baseline: 2.3921x; 2.3921x over previous
//
#include <hip/hip_runtime.h>
#include <hip/hip_bf16.h>
#include <cstddef>
#include <cstdint>

typedef __attribute__((ext_vector_type(8))) short short8;
typedef __attribute__((ext_vector_type(4))) float floatx4;
typedef __hip_bfloat16 bf16;

// Problem constants
#define BATCH 2
#define HEADS 8
#define TOK   65536      // total tokens
#define CH    32768      // tokens per chunk (1/2); == one batch's windows
#define OUTC  256

// ---------------------------------------------------------------------------
// Transpose input (B,C,32,32,32) -> token-major xbuf[(b*32768+sp)*128 + c]
// ---------------------------------------------------------------------------
__global__ __launch_bounds__(256) void transpose_in_kernel(
    const float* __restrict__ x, float* __restrict__ out)
{
    __shared__ float tile[128 * 65];
    int chunk = blockIdx.x;            // 1024 blocks: 512 per batch, 64 sp each
    int tid = threadIdx.x;
    int b = chunk >> 9;
    int sp0 = (chunk & 511) * 64;
    #pragma unroll
    for (int l = 0; l < 32; ++l) {
        int idx = l * 256 + tid;
        int c = idx >> 6;
        int s = idx & 63;
        tile[c * 65 + s] = x[(((size_t)(b * 128 + c)) << 15) + sp0 + s];
    }
    __syncthreads();
    #pragma unroll
    for (int l = 0; l < 32; ++l) {
        int idx = l * 256 + tid;
        int s = idx >> 7;
        int c = idx & 127;
        out[((size_t)((b << 15) + sp0 + s)) * 128 + c] = tile[c * 65 + s];
    }
}

// fp32 -> bf16 elementwise (weights)
__global__ void f2bf_kernel(const float* __restrict__ src, bf16* __restrict__ dst, int n)
{
    int i = blockIdx.x * blockDim.x + threadIdx.x;
    if (i < n) dst[i] = __float2bfloat16(src[i]);
}

// ---------------------------------------------------------------------------
// LayerNorm + cyclic shift + window partition (gather) -> bf16 chunk.
// grid = CH, block = 64.
// ---------------------------------------------------------------------------
__global__ __launch_bounds__(64) void ln_window_kernel(
    const float* __restrict__ x, bf16* __restrict__ out,
    const float* __restrict__ g, const float* __restrict__ bta, int shift, int m0)
{
    int m = m0 + blockIdx.x;
    int tid = threadIdx.x;
    int n = m & 63, w = (m >> 6) & 511, b = m >> 15;
    int ih = n >> 4, iw = (n >> 2) & 3, it = n & 3;
    int wh = w >> 6, ww = (w >> 3) & 7, wt = w & 7;
    int h  = (wh * 4 + ih + shift) & 31;
    int w2 = (ww * 4 + iw + shift) & 31;
    int t  = (wt * 4 + it + shift) & 31;
    size_t tok = ((size_t)b << 15) + ((h * 32 + w2) * 32 + t);
    const float* xp = x + tok * 128;
    float v0 = xp[tid], v1 = xp[tid + 64];
    float s = v0 + v1, sq = v0 * v0 + v1 * v1;
    #pragma unroll
    for (int o = 32; o > 0; o >>= 1) { s += __shfl_xor(s, o); sq += __shfl_xor(sq, o); }
    float mu  = s * (1.0f / 128.0f);
    float var = sq * (1.0f / 128.0f) - mu * mu;
    float rs  = rsqrtf(var + 1e-5f);
    bf16* op = out + (size_t)blockIdx.x * 128;
    op[tid]      = __float2bfloat16((v0 - mu) * rs * g[tid]      + bta[tid]);
    op[tid + 64] = __float2bfloat16((v1 - mu) * rs * g[tid + 64] + bta[tid + 64]);
}

// Plain LayerNorm chunk -> bf16 (x pre-offset). grid = CH, block = 64
__global__ __launch_bounds__(64) void ln_plain_kernel(
    const float* __restrict__ x, bf16* __restrict__ out,
    const float* __restrict__ g, const float* __restrict__ bta)
{
    size_t tok = blockIdx.x;
    int tid = threadIdx.x;
    const float* xp = x + tok * 128;
    float v0 = xp[tid], v1 = xp[tid + 64];
    float s = v0 + v1, sq = v0 * v0 + v1 * v1;
    #pragma unroll
    for (int o = 32; o > 0; o >>= 1) { s += __shfl_xor(s, o); sq += __shfl_xor(sq, o); }
    float mu  = s * (1.0f / 128.0f);
    float var = sq * (1.0f / 128.0f) - mu * mu;
    float rs  = rsqrtf(var + 1e-5f);
    bf16* op = out + tok * 128;
    op[tid]      = __float2bfloat16((v0 - mu) * rs * g[tid]      + bta[tid]);
    op[tid + 64] = __float2bfloat16((v1 - mu) * rs * g[tid + 64] + bta[tid + 64]);
}

// ---------------------------------------------------------------------------
// bf16 MFMA GEMM: V[M,N] = A[M,K] @ B[N,K]^T + bias, fused epilogues.
// 128x128 tile, 256 threads = 4 waves (2x2 of 64x64), BK=32,
// mfma_f32_16x16x32_bf16. M,N multiples of 128; K multiple of 32.
// mode 0: Cb[m*N+n] = bf16(v)
// mode 1: Cb[m*N+n] = bf16(gelu(v))
// mode 2: scatter-add (un-shift window) into aux fp32: aux[tok*128+n] += v
// mode 3: aux[(m0+m)*128+n] += v
// mode 4: BN stats: aux[n] += v, aux[256+n] += v^2
// mode 5: BN+ReLU+transpose: Cf = d_out, aux = stats, p1 = bn_g, p2 = bn_b
// ---------------------------------------------------------------------------
__global__ __launch_bounds__(256) void gemm_bf16_kernel(
    const bf16* __restrict__ A, const bf16* __restrict__ Bw,
    const float* __restrict__ bias, bf16* __restrict__ Cb, float* __restrict__ Cf,
    float* __restrict__ aux, const float* __restrict__ p1, const float* __restrict__ p2,
    int M, int N, int K, int mode, int m0, int shift)
{
    __shared__ short As[128 * 32];
    __shared__ short Bs[128 * 32];
    __shared__ float cs[128];
    __shared__ float cq[128];
    int tid = threadIdx.x;
    int lane = tid & 63, wv = tid >> 6;
    int wm = wv >> 1, wn = wv & 1;
    int ln15 = lane & 15, quad = lane >> 4;
    int q8 = quad * 8;
    int nBase = blockIdx.x * 128;
    int mBase = blockIdx.y * 128;
    floatx4 acc[4][4] = {};

    if (mode == 4 && tid < 128) { cs[tid] = 0.f; cq[tid] = 0.f; }

    int srow = tid >> 2, scb = tid & 3;   // staging: row within tile, 16B chunk
    for (int k0 = 0; k0 < K; k0 += 32) {
        #pragma unroll
        for (int i = 0; i < 2; ++i) {
            int row = srow + i * 64;
            ((uint4*)As)[i * 256 + tid] =
                *(const uint4*)(A + (size_t)(mBase + row) * K + k0 + scb * 8);
            ((uint4*)Bs)[i * 256 + tid] =
                *(const uint4*)(Bw + (size_t)(nBase + row) * K + k0 + scb * 8);
        }
        __syncthreads();
        short8 af[4], bfr[4];
        #pragma unroll
        for (int mt = 0; mt < 4; ++mt)
            af[mt] = *(const short8*)&As[(wm * 64 + mt * 16 + ln15) * 32 + q8];
        #pragma unroll
        for (int nt = 0; nt < 4; ++nt)
            bfr[nt] = *(const short8*)&Bs[(wn * 64 + nt * 16 + ln15) * 32 + q8];
        #pragma unroll
        for (int mt = 0; mt < 4; ++mt)
            #pragma unroll
            for (int nt = 0; nt < 4; ++nt)
                acc[mt][nt] = __builtin_amdgcn_mfma_f32_16x16x32_bf16(
                    af[mt], bfr[nt], acc[mt][nt], 0, 0, 0);
        __syncthreads();
    }

    if (mode == 4) {
        #pragma unroll
        for (int nt = 0; nt < 4; ++nt) {
            int nl = wn * 64 + nt * 16 + ln15;
            float bs = bias[nBase + nl];
            float s = 0.f, sq = 0.f;
            #pragma unroll
            for (int mt = 0; mt < 4; ++mt)
                #pragma unroll
                for (int r = 0; r < 4; ++r) {
                    float v = acc[mt][nt][r] + bs;
                    s += v; sq += v * v;
                }
            atomicAdd(&cs[nl], s);
            atomicAdd(&cq[nl], sq);
        }
        __syncthreads();
        if (tid < 128) {
            atomicAdd(&aux[nBase + tid], cs[tid]);
            atomicAdd(&aux[256 + nBase + tid], cq[tid]);
        }
        return;
    }

    #pragma unroll
    for (int mt = 0; mt < 4; ++mt) {
        #pragma unroll
        for (int r = 0; r < 4; ++r) {
            int m = mBase + wm * 64 + mt * 16 + quad * 4 + r;
            #pragma unroll
            for (int nt = 0; nt < 4; ++nt) {
                int nn = nBase + wn * 64 + nt * 16 + ln15;
                float v = acc[mt][nt][r] + bias[nn];
                if (mode == 0) {
                    Cb[(size_t)m * N + nn] = __float2bfloat16(v);
                } else if (mode == 1) {
                    v = 0.5f * v * (1.0f + erff(v * 0.70710678118654752f));
                    Cb[(size_t)m * N + nn] = __float2bfloat16(v);
                } else if (mode == 2) {
                    int g = m0 + m;
                    int n_ = g & 63, w = (g >> 6) & 511, b = g >> 15;
                    int ih = n_ >> 4, iw = (n_ >> 2) & 3, it = n_ & 3;
                    int wh = w >> 6, ww = (w >> 3) & 7, wt = w & 7;
                    int h  = (wh * 4 + ih + shift) & 31;
                    int w2 = (ww * 4 + iw + shift) & 31;
                    int t  = (wt * 4 + it + shift) & 31;
                    size_t tok = ((size_t)b << 15) + ((h * 32 + w2) * 32 + t);
                    aux[tok * 128 + nn] += v;
                } else if (mode == 3) {
                    aux[(size_t)(m0 + m) * 128 + nn] += v;
                } else { // mode 5
                    int g = m0 + m;
                    int b = g >> 15, sp = g & 32767;
                    float mean = aux[nn] * (1.0f / 65536.0f);
                    float var  = aux[256 + nn] * (1.0f / 65536.0f) - mean * mean;
                    float y = (v - mean) * rsqrtf(var + 1e-5f) * p1[nn] + p2[nn];
                    Cf[(((size_t)(b * 256 + nn)) << 15) + sp] = fmaxf(y, 0.f);
                }
            }
        }
    }
}

// ---------------------------------------------------------------------------
// Windowed attention (bf16 in/out): one block per (window-in-chunk, head).
// ---------------------------------------------------------------------------
__global__ __launch_bounds__(64) void attn_kernel(
    const bf16* __restrict__ qkv, const float* __restrict__ rpb,
    bf16* __restrict__ outp, int shift, int wBase)
{
    __shared__ float kt[64][16];
    __shared__ float vt[64][16];
    __shared__ float rp[343];
    __shared__ int   cnt[64];
    int blk = blockIdx.x;
    int head = blk & 7;
    int lw = blk >> 3;
    int i = threadIdx.x;
    const bf16* base = qkv + (size_t)(lw * 64) * 384 + head * 16;
    float q[16];
    #pragma unroll
    for (int d = 0; d < 16; ++d) q[d] = __bfloat162float(base[(size_t)i * 384 + d]) * 0.25f;
    #pragma unroll
    for (int d = 0; d < 16; ++d) kt[i][d] = __bfloat162float(base[(size_t)i * 384 + 128 + d]);
    #pragma unroll
    for (int d = 0; d < 16; ++d) vt[i][d] = __bfloat162float(base[(size_t)i * 384 + 256 + d]);
    for (int j = i; j < 343; j += 64) rp[j] = rpb[(size_t)j * 8 + head];
    int w = (wBase + lw) & 511;
    int ih = i >> 4, iw = (i >> 2) & 3, it = i & 3;
    if (shift) {
        int wh = w >> 6, ww = (w >> 3) & 7, wt = w & 7;
        int h = wh * 4 + ih, w2 = ww * 4 + iw, t = wt * 4 + it;
        int rh = (h  < 28) ? 0 : ((h  < 30) ? 1 : 2);
        int rw = (w2 < 28) ? 0 : ((w2 < 30) ? 1 : 2);
        int rt = (t  < 28) ? 0 : ((t  < 30) ? 1 : 2);
        cnt[i] = (rh * 3 + rw) * 3 + rt;
    }
    __syncthreads();
    float logits[64];
    int ci = shift ? cnt[i] : 0;
    #pragma unroll
    for (int j = 0; j < 64; ++j) {
        float d0 = 0.f;
        #pragma unroll
        for (int d = 0; d < 16; ++d) d0 += q[d] * kt[j][d];
        int jh = j >> 4, jw = (j >> 2) & 3, jt = j & 3;
        int ridx = ((ih - jh + 3) * 7 + (iw - jw + 3)) * 7 + (it - jt + 3);
        d0 += rp[ridx];
        if (shift && cnt[j] != ci) d0 -= 100.0f;
        logits[j] = d0;
    }
    float mx = -1e30f;
    #pragma unroll
    for (int j = 0; j < 64; ++j) mx = fmaxf(mx, logits[j]);
    float ssum = 0.f;
    #pragma unroll
    for (int j = 0; j < 64; ++j) { float e = __expf(logits[j] - mx); logits[j] = e; ssum += e; }
    float inv = 1.0f / ssum;
    float o[16] = {};
    #pragma unroll
    for (int j = 0; j < 64; ++j) {
        float p = logits[j] * inv;
        #pragma unroll
        for (int d = 0; d < 16; ++d) o[d] += p * vt[j][d];
    }
    bf16* op = outp + (size_t)(lw * 64 + i) * 128 + head * 16;
    #pragma unroll
    for (int d = 0; d < 16; ++d) op[d] = __float2bfloat16(o[d]);
}

// ---------------------------------------------------------------------------
// Depthwise 3x3x3 conv, SAME zero-pad, full volume -> bf16. grid = TOK, blk 128
// ---------------------------------------------------------------------------
__global__ __launch_bounds__(128) void dwconv_kernel(
    const float* __restrict__ x, const float* __restrict__ wgt,
    const float* __restrict__ bias, bf16* __restrict__ out)
{
    int tok = blockIdx.x;
    int c = threadIdx.x;
    int sp = tok & 32767, b = tok >> 15;
    int t = sp & 31, w = (sp >> 5) & 31, h = sp >> 10;
    float acc = bias[c];
    #pragma unroll
    for (int kh = -1; kh <= 1; ++kh) {
        int hh = h + kh; if (hh < 0 || hh > 31) continue;
        #pragma unroll
        for (int kw = -1; kw <= 1; ++kw) {
            int ww = w + kw; if (ww < 0 || ww > 31) continue;
            #pragma unroll
            for (int kt = -1; kt <= 1; ++kt) {
                int tt = t + kt; if (tt < 0 || tt > 31) continue;
                size_t ntok = ((size_t)b << 15) + ((hh * 32 + ww) * 32 + tt);
                acc += x[ntok * 128 + c] * wgt[c * 27 + ((kh + 1) * 3 + (kw + 1)) * 3 + (kt + 1)];
            }
        }
    }
    out[(size_t)tok * 128 + c] = __float2bfloat16(acc);
}

__global__ void zero_kernel(float* __restrict__ p, int n)
{
    int i = blockIdx.x * blockDim.x + threadIdx.x;
    if (i < n) p[i] = 0.f;
}

// ---------------------------------------------------------------------------
extern "C" void kernel_launch(void* const* d_in, const int* in_sizes, int n_in,
                              void* d_out, int out_size, void* d_ws, size_t ws_size,
                              hipStream_t stream)
{
    const float* x_in    = (const float*)d_in[0];
    const float* norm1_g = (const float*)d_in[1];
    const float* norm1_b = (const float*)d_in[2];
    const float* qkv_w   = (const float*)d_in[3];
    const float* qkv_b   = (const float*)d_in[4];
    const float* proj_w  = (const float*)d_in[5];
    const float* proj_b  = (const float*)d_in[6];
    const float* rpb     = (const float*)d_in[7];
    const float* norm2_g = (const float*)d_in[8];
    const float* norm2_b = (const float*)d_in[9];
    const float* fc1_w   = (const float*)d_in[10];
    const float* fc1_b   = (const float*)d_in[11];
    const float* fc2_w   = (const float*)d_in[12];
    const float* fc2_b   = (const float*)d_in[13];
    const float* dw_w    = (const float*)d_in[14];
    const float* dw_b    = (const float*)d_in[15];
    const float* pw_w    = (const float*)d_in[16];
    const float* pw_b    = (const float*)d_in[17];
    const float* bn_g    = (const float*)d_in[18];
    const float* bn_b    = (const float*)d_in[19];
    float* out = (float*)d_out;

    // Workspace layout — total 76 MB
    char* ws = (char*)d_ws;
    float* xbuf   = (float*)ws;                         // 32 MB [TOK,128] fp32
    bf16*  wbf    = (bf16*)(ws + 33554432ULL);          // 1.6 MB bf16 weights
    float* stats  = (float*)(ws + 35651584ULL);         // 2 KB
    char*  S      = ws + 37748736ULL;
    bf16*  lnbuf  = (bf16*)S;                           // 8 MB  [CH,128]
    bf16*  qkvbuf = (bf16*)(S + 8388608ULL);            // 24 MB [CH,384]
    bf16*  attnbuf= (bf16*)(S + 33554432ULL);           // 8 MB  [CH,128]
    bf16*  hidbuf = (bf16*)(S + 8388608ULL);            // 32 MB [CH,512] (overlap, MLP phase)
    bf16*  dwbuf  = (bf16*)(S + 8388608ULL);            // 16 MB [TOK,128] (connect phase)

    bf16* wqkv = wbf;                 // 4 x 384 x 128
    bf16* wproj = wbf + 196608;       // 4 x 128 x 128
    bf16* wfc1 = wbf + 262144;        // 4 x 512 x 128
    bf16* wfc2 = wbf + 524288;        // 4 x 128 x 512
    bf16* wpw  = wbf + 786432;        // 256 x 128

    // Weight conversions (same work every call; graph-safe)
    hipLaunchKernelGGL(f2bf_kernel, dim3(768), dim3(256), 0, stream, qkv_w, wqkv, 196608);
    hipLaunchKernelGGL(f2bf_kernel, dim3(256), dim3(256), 0, stream, proj_w, wproj, 65536);
    hipLaunchKernelGGL(f2bf_kernel, dim3(1024), dim3(256), 0, stream, fc1_w, wfc1, 262144);
    hipLaunchKernelGGL(f2bf_kernel, dim3(1024), dim3(256), 0, stream, fc2_w, wfc2, 262144);
    hipLaunchKernelGGL(f2bf_kernel, dim3(128), dim3(256), 0, stream, pw_w, wpw, 32768);

    hipLaunchKernelGGL(transpose_in_kernel, dim3(1024), dim3(256), 0, stream, x_in, xbuf);

    const int shifts[4] = {0, 2, 0, 2};
    for (int i = 0; i < 4; ++i) {
        int s = shifts[i];
        // --- attention half (2 chunks of 512 windows / 32768 tokens) ---
        for (int c0 = 0; c0 < 2; ++c0) {
            int m0 = c0 * CH;
            hipLaunchKernelGGL(ln_window_kernel, dim3(CH), dim3(64), 0, stream,
                               xbuf, lnbuf, norm1_g + i * 128, norm1_b + i * 128, s, m0);
            hipLaunchKernelGGL(gemm_bf16_kernel, dim3(384 / 128, CH / 128), dim3(256), 0, stream,
                               lnbuf, wqkv + (size_t)i * 49152, qkv_b + i * 384,
                               qkvbuf, (float*)nullptr, (float*)nullptr,
                               (const float*)nullptr, (const float*)nullptr,
                               CH, 384, 128, 0, 0, 0);
            hipLaunchKernelGGL(attn_kernel, dim3(512 * HEADS), dim3(64), 0, stream,
                               qkvbuf, rpb + (size_t)i * 343 * 8, attnbuf, s, c0 * 512);
            hipLaunchKernelGGL(gemm_bf16_kernel, dim3(1, CH / 128), dim3(256), 0, stream,
                               attnbuf, wproj + (size_t)i * 16384, proj_b + i * 128,
                               (bf16*)nullptr, (float*)nullptr, xbuf,
                               (const float*)nullptr, (const float*)nullptr,
                               CH, 128, 128, 2, m0, s);
        }
        // --- MLP half ---
        for (int c0 = 0; c0 < 2; ++c0) {
            int m0 = c0 * CH;
            hipLaunchKernelGGL(ln_plain_kernel, dim3(CH), dim3(64), 0, stream,
                               xbuf + (size_t)m0 * 128, lnbuf, norm2_g + i * 128, norm2_b + i * 128);
            hipLaunchKernelGGL(gemm_bf16_kernel, dim3(512 / 128, CH / 128), dim3(256), 0, stream,
                               lnbuf, wfc1 + (size_t)i * 65536, fc1_b + i * 512,
                               hidbuf, (float*)nullptr, (float*)nullptr,
                               (const float*)nullptr, (const float*)nullptr,
                               CH, 512, 128, 1, 0, 0);
            hipLaunchKernelGGL(gemm_bf16_kernel, dim3(1, CH / 128), dim3(256), 0, stream,
                               hidbuf, wfc2 + (size_t)i * 65536, fc2_b + i * 128,
                               (bf16*)nullptr, (float*)nullptr, xbuf,
                               (const float*)nullptr, (const float*)nullptr,
                               CH, 128, 512, 3, m0, 0);
        }
    }

    // connectBlock: dwconv once -> bf16; two GEMM passes for BN
    hipLaunchKernelGGL(dwconv_kernel, dim3(TOK), dim3(128), 0, stream, xbuf, dw_w, dw_b, dwbuf);
    hipLaunchKernelGGL(zero_kernel, dim3(2), dim3(256), 0, stream, stats, 512);
    hipLaunchKernelGGL(gemm_bf16_kernel, dim3(OUTC / 128, TOK / 128), dim3(256), 0, stream,
                       dwbuf, wpw, pw_b,
                       (bf16*)nullptr, (float*)nullptr, stats,
                       (const float*)nullptr, (const float*)nullptr,
                       TOK, OUTC, 128, 4, 0, 0);
    hipLaunchKernelGGL(gemm_bf16_kernel, dim3(OUTC / 128, TOK / 128), dim3(256), 0, stream,
                       dwbuf, wpw, pw_b,
                       (bf16*)nullptr, out, stats,
                       bn_g, bn_b,
                       TOK, OUTC, 128, 5, 0, 0);
}

// Round 4
// 1350.587 us; speedup vs baseline: 3.3101x; 1.3838x over previous
//
#include <hip/hip_runtime.h>
#include <hip/hip_bf16.h>
#include <cstddef>
#include <cstdint>

typedef __attribute__((ext_vector_type(8))) short short8;
typedef __attribute__((ext_vector_type(4))) float floatx4;
typedef __hip_bfloat16 bf16;

#define HEADS 8
#define TOK   65536
#define OUTC  256

// ---------------------------------------------------------------------------
// Transpose input (B,C,32,32,32) -> token-major xbuf[(b*32768+sp)*128 + c]
// ---------------------------------------------------------------------------
__global__ __launch_bounds__(256) void transpose_in_kernel(
    const float* __restrict__ x, float* __restrict__ out)
{
    __shared__ float tile[128 * 65];
    int chunk = blockIdx.x;            // 1024 blocks: 512 per batch, 64 sp each
    int tid = threadIdx.x;
    int b = chunk >> 9;
    int sp0 = (chunk & 511) * 64;
    #pragma unroll
    for (int l = 0; l < 32; ++l) {
        int idx = l * 256 + tid;
        int c = idx >> 6;
        int s = idx & 63;
        tile[c * 65 + s] = x[(((size_t)(b * 128 + c)) << 15) + sp0 + s];
    }
    __syncthreads();
    #pragma unroll
    for (int l = 0; l < 32; ++l) {
        int idx = l * 256 + tid;
        int s = idx >> 7;
        int c = idx & 127;
        out[((size_t)((b << 15) + sp0 + s)) * 128 + c] = tile[c * 65 + s];
    }
}

// ---------------------------------------------------------------------------
// Prep: all weight fp32->bf16 conversions + dw-weight transpose + stats zero.
// grid = 3200 x 256 (819200 threads)
// ---------------------------------------------------------------------------
__global__ __launch_bounds__(256) void prep_kernel(
    const float* __restrict__ qkv_w, const float* __restrict__ proj_w,
    const float* __restrict__ fc1_w, const float* __restrict__ fc2_w,
    const float* __restrict__ pw_w, const float* __restrict__ dw_w,
    bf16* __restrict__ wbf, float* __restrict__ dwt, float* __restrict__ stats)
{
    int i = blockIdx.x * 256 + threadIdx.x;
    float v;
    if (i < 196608)       v = qkv_w[i];
    else if (i < 262144)  v = proj_w[i - 196608];
    else if (i < 524288)  v = fc1_w[i - 262144];
    else if (i < 786432)  v = fc2_w[i - 524288];
    else                  v = pw_w[i - 786432];
    wbf[i] = __float2bfloat16(v);
    if (i < 3456) {
        int c = i / 27, k = i % 27;
        dwt[k * 128 + c] = dw_w[i];
    }
    if (i < 512) stats[i] = 0.f;
}

// ---------------------------------------------------------------------------
// LayerNorm + cyclic shift + window partition -> bf16. 4 tokens per block.
// grid = TOK/4, block = 256 (one wave per token)
// ---------------------------------------------------------------------------
__global__ __launch_bounds__(256) void ln_window_kernel(
    const float* __restrict__ x, bf16* __restrict__ out,
    const float* __restrict__ g, const float* __restrict__ bta, int shift)
{
    int m = blockIdx.x * 4 + (threadIdx.x >> 6);
    int lane = threadIdx.x & 63;
    int n = m & 63, w = (m >> 6) & 511, b = m >> 15;
    int ih = n >> 4, iw = (n >> 2) & 3, it = n & 3;
    int wh = w >> 6, ww = (w >> 3) & 7, wt = w & 7;
    int h  = (wh * 4 + ih + shift) & 31;
    int w2 = (ww * 4 + iw + shift) & 31;
    int t  = (wt * 4 + it + shift) & 31;
    size_t tok = ((size_t)b << 15) + ((h * 32 + w2) * 32 + t);
    const float* xp = x + tok * 128;
    float v0 = xp[lane], v1 = xp[lane + 64];
    float s = v0 + v1, sq = v0 * v0 + v1 * v1;
    #pragma unroll
    for (int o = 32; o > 0; o >>= 1) { s += __shfl_xor(s, o); sq += __shfl_xor(sq, o); }
    float mu  = s * (1.0f / 128.0f);
    float var = sq * (1.0f / 128.0f) - mu * mu;
    float rs  = rsqrtf(var + 1e-5f);
    bf16* op = out + (size_t)m * 128;
    op[lane]      = __float2bfloat16((v0 - mu) * rs * g[lane]      + bta[lane]);
    op[lane + 64] = __float2bfloat16((v1 - mu) * rs * g[lane + 64] + bta[lane + 64]);
}

// Plain LayerNorm -> bf16, 4 tokens per block. grid = TOK/4
__global__ __launch_bounds__(256) void ln_plain_kernel(
    const float* __restrict__ x, bf16* __restrict__ out,
    const float* __restrict__ g, const float* __restrict__ bta)
{
    size_t tok = blockIdx.x * 4 + (threadIdx.x >> 6);
    int lane = threadIdx.x & 63;
    const float* xp = x + tok * 128;
    float v0 = xp[lane], v1 = xp[lane + 64];
    float s = v0 + v1, sq = v0 * v0 + v1 * v1;
    #pragma unroll
    for (int o = 32; o > 0; o >>= 1) { s += __shfl_xor(s, o); sq += __shfl_xor(sq, o); }
    float mu  = s * (1.0f / 128.0f);
    float var = sq * (1.0f / 128.0f) - mu * mu;
    float rs  = rsqrtf(var + 1e-5f);
    bf16* op = out + tok * 128;
    op[lane]      = __float2bfloat16((v0 - mu) * rs * g[lane]      + bta[lane]);
    op[lane + 64] = __float2bfloat16((v1 - mu) * rs * g[lane + 64] + bta[lane + 64]);
}

// ---------------------------------------------------------------------------
// bf16 MFMA GEMM: V[M,N] = A[M,K] @ B[N,K]^T + bias, fused epilogues.
// 128x128 tile, 256 threads = 4 waves (2x2 of 64x64), BK=32.
// mode 0: Cb = bf16(v)
// mode 1: Cb = bf16(gelu(v))
// mode 2: scatter-add (un-shift window) into aux fp32
// mode 3: aux[m*128+n] += v; if Cb, also Cb[m*128+n] = bf16(new x)
// mode 4: BN stats: aux[n] += v, aux[256+n] += v^2
// mode 5: BN+ReLU+transpose: Cf = d_out, aux = stats, p1 = bn_g, p2 = bn_b
// ---------------------------------------------------------------------------
__global__ __launch_bounds__(256) void gemm_bf16_kernel(
    const bf16* __restrict__ A, const bf16* __restrict__ Bw,
    const float* __restrict__ bias, bf16* __restrict__ Cb, float* __restrict__ Cf,
    float* __restrict__ aux, const float* __restrict__ p1, const float* __restrict__ p2,
    int M, int N, int K, int mode, int shift)
{
    __shared__ short As[128 * 32];
    __shared__ short Bs[128 * 32];
    __shared__ float cs[128];
    __shared__ float cq[128];
    int tid = threadIdx.x;
    int lane = tid & 63, wv = tid >> 6;
    int wm = wv >> 1, wn = wv & 1;
    int ln15 = lane & 15, quad = lane >> 4;
    int q8 = quad * 8;
    int nBase = blockIdx.x * 128;
    int mBase = blockIdx.y * 128;
    floatx4 acc[4][4] = {};

    if (mode == 4 && tid < 128) { cs[tid] = 0.f; cq[tid] = 0.f; }

    int srow = tid >> 2, scb = tid & 3;
    for (int k0 = 0; k0 < K; k0 += 32) {
        #pragma unroll
        for (int i = 0; i < 2; ++i) {
            int row = srow + i * 64;
            ((uint4*)As)[i * 256 + tid] =
                *(const uint4*)(A + (size_t)(mBase + row) * K + k0 + scb * 8);
            ((uint4*)Bs)[i * 256 + tid] =
                *(const uint4*)(Bw + (size_t)(nBase + row) * K + k0 + scb * 8);
        }
        __syncthreads();
        short8 af[4], bfr[4];
        #pragma unroll
        for (int mt = 0; mt < 4; ++mt)
            af[mt] = *(const short8*)&As[(wm * 64 + mt * 16 + ln15) * 32 + q8];
        #pragma unroll
        for (int nt = 0; nt < 4; ++nt)
            bfr[nt] = *(const short8*)&Bs[(wn * 64 + nt * 16 + ln15) * 32 + q8];
        #pragma unroll
        for (int mt = 0; mt < 4; ++mt)
            #pragma unroll
            for (int nt = 0; nt < 4; ++nt)
                acc[mt][nt] = __builtin_amdgcn_mfma_f32_16x16x32_bf16(
                    af[mt], bfr[nt], acc[mt][nt], 0, 0, 0);
        __syncthreads();
    }

    if (mode == 4) {
        #pragma unroll
        for (int nt = 0; nt < 4; ++nt) {
            int nl = wn * 64 + nt * 16 + ln15;
            float bs = bias[nBase + nl];
            float s = 0.f, sq = 0.f;
            #pragma unroll
            for (int mt = 0; mt < 4; ++mt)
                #pragma unroll
                for (int r = 0; r < 4; ++r) {
                    float v = acc[mt][nt][r] + bs;
                    s += v; sq += v * v;
                }
            atomicAdd(&cs[nl], s);
            atomicAdd(&cq[nl], sq);
        }
        __syncthreads();
        if (tid < 128) {
            atomicAdd(&aux[nBase + tid], cs[tid]);
            atomicAdd(&aux[256 + nBase + tid], cq[tid]);
        }
        return;
    }

    #pragma unroll
    for (int mt = 0; mt < 4; ++mt) {
        #pragma unroll
        for (int r = 0; r < 4; ++r) {
            int m = mBase + wm * 64 + mt * 16 + quad * 4 + r;
            #pragma unroll
            for (int nt = 0; nt < 4; ++nt) {
                int nn = nBase + wn * 64 + nt * 16 + ln15;
                float v = acc[mt][nt][r] + bias[nn];
                if (mode == 0) {
                    Cb[(size_t)m * N + nn] = __float2bfloat16(v);
                } else if (mode == 1) {
                    v = 0.5f * v * (1.0f + erff(v * 0.70710678118654752f));
                    Cb[(size_t)m * N + nn] = __float2bfloat16(v);
                } else if (mode == 2) {
                    int n_ = m & 63, w = (m >> 6) & 511, b = m >> 15;
                    int ih = n_ >> 4, iw = (n_ >> 2) & 3, it = n_ & 3;
                    int wh = w >> 6, ww = (w >> 3) & 7, wt = w & 7;
                    int h  = (wh * 4 + ih + shift) & 31;
                    int w2 = (ww * 4 + iw + shift) & 31;
                    int t  = (wt * 4 + it + shift) & 31;
                    size_t tok = ((size_t)b << 15) + ((h * 32 + w2) * 32 + t);
                    aux[tok * 128 + nn] += v;
                } else if (mode == 3) {
                    float xn = aux[(size_t)m * 128 + nn] + v;
                    aux[(size_t)m * 128 + nn] = xn;
                    if (Cb) Cb[(size_t)m * 128 + nn] = __float2bfloat16(xn);
                } else { // mode 5
                    int b = m >> 15, sp = m & 32767;
                    float mean = aux[nn] * (1.0f / 65536.0f);
                    float var  = aux[256 + nn] * (1.0f / 65536.0f) - mean * mean;
                    float y = (v - mean) * rsqrtf(var + 1e-5f) * p1[nn] + p2[nn];
                    Cf[(((size_t)(b * 256 + nn)) << 15) + sp] = fmaxf(y, 0.f);
                }
            }
        }
    }
}

// ---------------------------------------------------------------------------
// Windowed attention (bf16 in/out): one block per (global window, head).
// grid = 1024*8
// ---------------------------------------------------------------------------
__global__ __launch_bounds__(64) void attn_kernel(
    const bf16* __restrict__ qkv, const float* __restrict__ rpb,
    bf16* __restrict__ outp, int shift)
{
    __shared__ float kt[64][16];
    __shared__ float vt[64][16];
    __shared__ float rp[343];
    __shared__ int   cnt[64];
    int blk = blockIdx.x;
    int head = blk & 7;
    int lw = blk >> 3;                 // global window 0..1023
    int i = threadIdx.x;
    const bf16* base = qkv + (size_t)(lw * 64) * 384 + head * 16;
    float q[16];
    #pragma unroll
    for (int d = 0; d < 16; ++d) q[d] = __bfloat162float(base[(size_t)i * 384 + d]) * 0.25f;
    #pragma unroll
    for (int d = 0; d < 16; ++d) kt[i][d] = __bfloat162float(base[(size_t)i * 384 + 128 + d]);
    #pragma unroll
    for (int d = 0; d < 16; ++d) vt[i][d] = __bfloat162float(base[(size_t)i * 384 + 256 + d]);
    for (int j = i; j < 343; j += 64) rp[j] = rpb[(size_t)j * 8 + head];
    int w = lw & 511;
    int ih = i >> 4, iw = (i >> 2) & 3, it = i & 3;
    if (shift) {
        int wh = w >> 6, ww = (w >> 3) & 7, wt = w & 7;
        int h = wh * 4 + ih, w2 = ww * 4 + iw, t = wt * 4 + it;
        int rh = (h  < 28) ? 0 : ((h  < 30) ? 1 : 2);
        int rw = (w2 < 28) ? 0 : ((w2 < 30) ? 1 : 2);
        int rt = (t  < 28) ? 0 : ((t  < 30) ? 1 : 2);
        cnt[i] = (rh * 3 + rw) * 3 + rt;
    }
    __syncthreads();
    float logits[64];
    int ci = shift ? cnt[i] : 0;
    #pragma unroll
    for (int j = 0; j < 64; ++j) {
        float d0 = 0.f;
        #pragma unroll
        for (int d = 0; d < 16; ++d) d0 += q[d] * kt[j][d];
        int jh = j >> 4, jw = (j >> 2) & 3, jt = j & 3;
        int ridx = ((ih - jh + 3) * 7 + (iw - jw + 3)) * 7 + (it - jt + 3);
        d0 += rp[ridx];
        if (shift && cnt[j] != ci) d0 -= 100.0f;
        logits[j] = d0;
    }
    float mx = -1e30f;
    #pragma unroll
    for (int j = 0; j < 64; ++j) mx = fmaxf(mx, logits[j]);
    float ssum = 0.f;
    #pragma unroll
    for (int j = 0; j < 64; ++j) { float e = __expf(logits[j] - mx); logits[j] = e; ssum += e; }
    float inv = 1.0f / ssum;
    float o[16] = {};
    #pragma unroll
    for (int j = 0; j < 64; ++j) {
        float p = logits[j] * inv;
        #pragma unroll
        for (int d = 0; d < 16; ++d) o[d] += p * vt[j][d];
    }
    bf16* op = outp + (size_t)(lw * 64 + i) * 128 + head * 16;
    #pragma unroll
    for (int d = 0; d < 16; ++d) op[d] = __float2bfloat16(o[d]);
}

// ---------------------------------------------------------------------------
// Depthwise 3x3x3 conv, bf16 in/out, register t-window reuse.
// grid = 2048 (b,h,w), block = 512 = 128 ch x 4 t-octets.
// dwt layout: [27][128] fp32.
// ---------------------------------------------------------------------------
__global__ __launch_bounds__(512) void dwconv_kernel(
    const bf16* __restrict__ x, const float* __restrict__ dwt,
    const float* __restrict__ bias, bf16* __restrict__ out)
{
    int blk = blockIdx.x;
    int b = blk >> 10;
    int h = (blk >> 5) & 31;
    int w = blk & 31;
    int tid = threadIdx.x;
    int c = tid & 127;
    int t0 = (tid >> 7) * 8;
    float acc[8];
    float bs = bias[c];
    #pragma unroll
    for (int o = 0; o < 8; ++o) acc[o] = bs;
    #pragma unroll
    for (int kh = 0; kh < 3; ++kh) {
        int hh = h + kh - 1;
        if (hh < 0 || hh > 31) continue;
        #pragma unroll
        for (int kw = 0; kw < 3; ++kw) {
            int ww = w + kw - 1;
            if (ww < 0 || ww > 31) continue;
            const bf16* px = x + (((size_t)(b << 15) + (hh * 32 + ww) * 32) * 128) + c;
            float v[10];
            #pragma unroll
            for (int u = 0; u < 10; ++u) {
                int tt = t0 - 1 + u;
                v[u] = (tt >= 0 && tt < 32) ? __bfloat162float(px[(size_t)tt * 128]) : 0.f;
            }
            float w0 = dwt[((kh * 3 + kw) * 3 + 0) * 128 + c];
            float w1 = dwt[((kh * 3 + kw) * 3 + 1) * 128 + c];
            float w2 = dwt[((kh * 3 + kw) * 3 + 2) * 128 + c];
            #pragma unroll
            for (int o = 0; o < 8; ++o)
                acc[o] += v[o] * w0 + v[o + 1] * w1 + v[o + 2] * w2;
        }
    }
    bf16* po = out + (((size_t)(b << 15) + (h * 32 + w) * 32 + t0) * 128) + c;
    #pragma unroll
    for (int o = 0; o < 8; ++o) po[(size_t)o * 128] = __float2bfloat16(acc[o]);
}

// ---------------------------------------------------------------------------
extern "C" void kernel_launch(void* const* d_in, const int* in_sizes, int n_in,
                              void* d_out, int out_size, void* d_ws, size_t ws_size,
                              hipStream_t stream)
{
    const float* x_in    = (const float*)d_in[0];
    const float* norm1_g = (const float*)d_in[1];
    const float* norm1_b = (const float*)d_in[2];
    const float* qkv_w   = (const float*)d_in[3];
    const float* qkv_b   = (const float*)d_in[4];
    const float* proj_w  = (const float*)d_in[5];
    const float* proj_b  = (const float*)d_in[6];
    const float* rpb     = (const float*)d_in[7];
    const float* norm2_g = (const float*)d_in[8];
    const float* norm2_b = (const float*)d_in[9];
    const float* fc1_w   = (const float*)d_in[10];
    const float* fc1_b   = (const float*)d_in[11];
    const float* fc2_w   = (const float*)d_in[12];
    const float* fc2_b   = (const float*)d_in[13];
    const float* dw_w    = (const float*)d_in[14];
    const float* dw_b    = (const float*)d_in[15];
    const float* pw_w    = (const float*)d_in[16];
    const float* pw_b    = (const float*)d_in[17];
    const float* bn_g    = (const float*)d_in[18];
    const float* bn_b    = (const float*)d_in[19];
    float* out = (float*)d_out;

    // Workspace layout (~132 MB)
    char* ws = (char*)d_ws;
    float* xbuf   = (float*)ws;                          // [0,32MB)   fp32 [TOK,128]
    bf16*  wbf    = (bf16*)(ws + 33554432ULL);           // [32,34MB)  bf16 weights
    float* dwt    = (float*)(ws + 35651584ULL);          // [34MB+..)  27x128 fp32
    float* stats  = (float*)(ws + 35651584ULL + 65536);  // 2 KB
    bf16*  lnbuf  = (bf16*)(ws + 37748736ULL);           // [36,52MB)  [TOK,128]
    bf16*  attnbuf= (bf16*)(ws + 54525952ULL);           // [52,68MB)  [TOK,128] (also dwbuf)
    bf16*  shared = (bf16*)(ws + 71303168ULL);           // [68,132MB) qkv[TOK,384] / hid[TOK,512]
    bf16*  qkvbuf = shared;
    bf16*  hidbuf = shared;
    bf16*  dwbuf  = attnbuf;                             // bf16 copy of final x
    bf16*  dcbuf  = lnbuf;                               // dwconv output (connect phase)

    bf16* wqkv  = wbf;                 // 4 x 384 x 128
    bf16* wproj = wbf + 196608;        // 4 x 128 x 128
    bf16* wfc1  = wbf + 262144;        // 4 x 512 x 128
    bf16* wfc2  = wbf + 524288;        // 4 x 128 x 512
    bf16* wpw   = wbf + 786432;        // 256 x 128

    hipLaunchKernelGGL(prep_kernel, dim3(3200), dim3(256), 0, stream,
                       qkv_w, proj_w, fc1_w, fc2_w, pw_w, dw_w, wbf, dwt, stats);
    hipLaunchKernelGGL(transpose_in_kernel, dim3(1024), dim3(256), 0, stream, x_in, xbuf);

    const int shifts[4] = {0, 2, 0, 2};
    for (int i = 0; i < 4; ++i) {
        int s = shifts[i];
        // --- attention half ---
        hipLaunchKernelGGL(ln_window_kernel, dim3(TOK / 4), dim3(256), 0, stream,
                           xbuf, lnbuf, norm1_g + i * 128, norm1_b + i * 128, s);
        hipLaunchKernelGGL(gemm_bf16_kernel, dim3(3, TOK / 128), dim3(256), 0, stream,
                           lnbuf, wqkv + (size_t)i * 49152, qkv_b + i * 384,
                           qkvbuf, (float*)nullptr, (float*)nullptr,
                           (const float*)nullptr, (const float*)nullptr,
                           TOK, 384, 128, 0, 0);
        hipLaunchKernelGGL(attn_kernel, dim3(1024 * HEADS), dim3(64), 0, stream,
                           qkvbuf, rpb + (size_t)i * 343 * 8, attnbuf, s);
        hipLaunchKernelGGL(gemm_bf16_kernel, dim3(1, TOK / 128), dim3(256), 0, stream,
                           attnbuf, wproj + (size_t)i * 16384, proj_b + i * 128,
                           (bf16*)nullptr, (float*)nullptr, xbuf,
                           (const float*)nullptr, (const float*)nullptr,
                           TOK, 128, 128, 2, s);
        // --- MLP half ---
        hipLaunchKernelGGL(ln_plain_kernel, dim3(TOK / 4), dim3(256), 0, stream,
                           xbuf, lnbuf, norm2_g + i * 128, norm2_b + i * 128);
        hipLaunchKernelGGL(gemm_bf16_kernel, dim3(4, TOK / 128), dim3(256), 0, stream,
                           lnbuf, wfc1 + (size_t)i * 65536, fc1_b + i * 512,
                           hidbuf, (float*)nullptr, (float*)nullptr,
                           (const float*)nullptr, (const float*)nullptr,
                           TOK, 512, 128, 1, 0);
        hipLaunchKernelGGL(gemm_bf16_kernel, dim3(1, TOK / 128), dim3(256), 0, stream,
                           hidbuf, wfc2 + (size_t)i * 65536, fc2_b + i * 128,
                           (i == 3) ? dwbuf : (bf16*)nullptr, (float*)nullptr, xbuf,
                           (const float*)nullptr, (const float*)nullptr,
                           TOK, 128, 512, 3, 0);
    }

    // connectBlock: dwconv (bf16) -> pointwise GEMM stats -> BN+ReLU GEMM
    hipLaunchKernelGGL(dwconv_kernel, dim3(2048), dim3(512), 0, stream,
                       dwbuf, dwt, dw_b, dcbuf);
    hipLaunchKernelGGL(gemm_bf16_kernel, dim3(OUTC / 128, TOK / 128), dim3(256), 0, stream,
                       dcbuf, wpw, pw_b,
                       (bf16*)nullptr, (float*)nullptr, stats,
                       (const float*)nullptr, (const float*)nullptr,
                       TOK, OUTC, 128, 4, 0);
    hipLaunchKernelGGL(gemm_bf16_kernel, dim3(OUTC / 128, TOK / 128), dim3(256), 0, stream,
                       dcbuf, wpw, pw_b,
                       (bf16*)nullptr, out, stats,
                       bn_g, bn_b,
                       TOK, OUTC, 128, 5, 0);
}

// Round 5
// 1180.220 us; speedup vs baseline: 3.7880x; 1.1444x over previous
//
#include <hip/hip_runtime.h>
#include <hip/hip_bf16.h>
#include <cstddef>
#include <cstdint>

typedef __attribute__((ext_vector_type(8))) short short8;
typedef __attribute__((ext_vector_type(4))) float floatx4;
typedef __hip_bfloat16 bf16;

#define HEADS 8
#define TOK   65536
#define OUTC  256

// ---------------------------------------------------------------------------
// Transpose input (B,C,32,32,32) -> token-major xbuf[(b*32768+sp)*128 + c]
// ---------------------------------------------------------------------------
__global__ __launch_bounds__(256) void transpose_in_kernel(
    const float* __restrict__ x, float* __restrict__ out)
{
    __shared__ float tile[128 * 65];
    int chunk = blockIdx.x;
    int tid = threadIdx.x;
    int b = chunk >> 9;
    int sp0 = (chunk & 511) * 64;
    #pragma unroll
    for (int l = 0; l < 32; ++l) {
        int idx = l * 256 + tid;
        int c = idx >> 6;
        int s = idx & 63;
        tile[c * 65 + s] = x[(((size_t)(b * 128 + c)) << 15) + sp0 + s];
    }
    __syncthreads();
    #pragma unroll
    for (int l = 0; l < 32; ++l) {
        int idx = l * 256 + tid;
        int s = idx >> 7;
        int c = idx & 127;
        out[((size_t)((b << 15) + sp0 + s)) * 128 + c] = tile[c * 65 + s];
    }
}

// ---------------------------------------------------------------------------
// Prep: weight fp32->bf16 conversions + dw-weight transpose + stats zero.
// ---------------------------------------------------------------------------
__global__ __launch_bounds__(256) void prep_kernel(
    const float* __restrict__ qkv_w, const float* __restrict__ proj_w,
    const float* __restrict__ fc1_w, const float* __restrict__ fc2_w,
    const float* __restrict__ pw_w, const float* __restrict__ dw_w,
    bf16* __restrict__ wbf, float* __restrict__ dwt, float* __restrict__ stats)
{
    int i = blockIdx.x * 256 + threadIdx.x;
    float v;
    if (i < 196608)       v = qkv_w[i];
    else if (i < 262144)  v = proj_w[i - 196608];
    else if (i < 524288)  v = fc1_w[i - 262144];
    else if (i < 786432)  v = fc2_w[i - 524288];
    else                  v = pw_w[i - 786432];
    wbf[i] = __float2bfloat16(v);
    if (i < 3456) {
        int c = i / 27, k = i % 27;
        dwt[k * 128 + c] = dw_w[i];
    }
    if (i < 512) stats[i] = 0.f;
}

// ---------------------------------------------------------------------------
// LayerNorm + cyclic shift + window partition -> bf16. 4 tokens per block.
// ---------------------------------------------------------------------------
__global__ __launch_bounds__(256) void ln_window_kernel(
    const float* __restrict__ x, bf16* __restrict__ out,
    const float* __restrict__ g, const float* __restrict__ bta, int shift)
{
    int m = blockIdx.x * 4 + (threadIdx.x >> 6);
    int lane = threadIdx.x & 63;
    int n = m & 63, w = (m >> 6) & 511, b = m >> 15;
    int ih = n >> 4, iw = (n >> 2) & 3, it = n & 3;
    int wh = w >> 6, ww = (w >> 3) & 7, wt = w & 7;
    int h  = (wh * 4 + ih + shift) & 31;
    int w2 = (ww * 4 + iw + shift) & 31;
    int t  = (wt * 4 + it + shift) & 31;
    size_t tok = ((size_t)b << 15) + ((h * 32 + w2) * 32 + t);
    const float* xp = x + tok * 128;
    float v0 = xp[lane], v1 = xp[lane + 64];
    float s = v0 + v1, sq = v0 * v0 + v1 * v1;
    #pragma unroll
    for (int o = 32; o > 0; o >>= 1) { s += __shfl_xor(s, o); sq += __shfl_xor(sq, o); }
    float mu  = s * (1.0f / 128.0f);
    float var = sq * (1.0f / 128.0f) - mu * mu;
    float rs  = rsqrtf(var + 1e-5f);
    bf16* op = out + (size_t)m * 128;
    op[lane]      = __float2bfloat16((v0 - mu) * rs * g[lane]      + bta[lane]);
    op[lane + 64] = __float2bfloat16((v1 - mu) * rs * g[lane + 64] + bta[lane + 64]);
}

// ---------------------------------------------------------------------------
// bf16 MFMA GEMM with coalesced LDS-staged epilogues.
// 128x128 tile, 256 threads = 4 waves (2x2 of 64x64), BK=32.
// mode 0: Cb[m*N+n] = bf16(v)                (LDS-staged row stores)
// mode 2: scatter-add (un-shift) into aux    (LDS-staged per-token f4 RMW)
// mode 4: BN stats: aux[n] += v, aux[256+n] += v^2
// mode 5: BN+ReLU+transpose to Cf            (LDS-transposed channel stores)
// ---------------------------------------------------------------------------
__global__ __launch_bounds__(256) void gemm_bf16_kernel(
    const bf16* __restrict__ A, const bf16* __restrict__ Bw,
    const float* __restrict__ bias, bf16* __restrict__ Cb, float* __restrict__ Cf,
    float* __restrict__ aux, const float* __restrict__ p1, const float* __restrict__ p2,
    int M, int N, int K, int mode, int shift)
{
    __shared__ __align__(16) char smem[34816];   // staging (16K) / epilogue (34K)
    __shared__ float cs[128];
    __shared__ float cq[128];
    short* As = (short*)smem;
    short* Bs = (short*)(smem + 8192);
    int tid = threadIdx.x;
    int lane = tid & 63, wv = tid >> 6;
    int wm = wv >> 1, wn = wv & 1;
    int ln15 = lane & 15, quad = lane >> 4;
    int q8 = quad * 8;
    int nBase = blockIdx.x * 128;
    int mBase = blockIdx.y * 128;
    floatx4 acc[4][4] = {};

    if (mode == 4 && tid < 128) { cs[tid] = 0.f; cq[tid] = 0.f; }

    int srow = tid >> 2, scb = tid & 3;
    for (int k0 = 0; k0 < K; k0 += 32) {
        #pragma unroll
        for (int i = 0; i < 2; ++i) {
            int row = srow + i * 64;
            ((uint4*)As)[i * 256 + tid] =
                *(const uint4*)(A + (size_t)(mBase + row) * K + k0 + scb * 8);
            ((uint4*)Bs)[i * 256 + tid] =
                *(const uint4*)(Bw + (size_t)(nBase + row) * K + k0 + scb * 8);
        }
        __syncthreads();
        short8 af[4], bfr[4];
        #pragma unroll
        for (int mt = 0; mt < 4; ++mt)
            af[mt] = *(const short8*)&As[(wm * 64 + mt * 16 + ln15) * 32 + q8];
        #pragma unroll
        for (int nt = 0; nt < 4; ++nt)
            bfr[nt] = *(const short8*)&Bs[(wn * 64 + nt * 16 + ln15) * 32 + q8];
        #pragma unroll
        for (int mt = 0; mt < 4; ++mt)
            #pragma unroll
            for (int nt = 0; nt < 4; ++nt)
                acc[mt][nt] = __builtin_amdgcn_mfma_f32_16x16x32_bf16(
                    af[mt], bfr[nt], acc[mt][nt], 0, 0, 0);
        __syncthreads();
    }

    if (mode == 4) {
        #pragma unroll
        for (int nt = 0; nt < 4; ++nt) {
            int nl = wn * 64 + nt * 16 + ln15;
            float bs = bias[nBase + nl];
            float s = 0.f, sq = 0.f;
            #pragma unroll
            for (int mt = 0; mt < 4; ++mt)
                #pragma unroll
                for (int r = 0; r < 4; ++r) {
                    float v = acc[mt][nt][r] + bs;
                    s += v; sq += v * v;
                }
            atomicAdd(&cs[nl], s);
            atomicAdd(&cq[nl], sq);
        }
        __syncthreads();
        if (tid < 128) {
            atomicAdd(&aux[nBase + tid], cs[tid]);
            atomicAdd(&aux[256 + nBase + tid], cq[tid]);
        }
        return;
    }

    if (mode == 0) {
        bf16* estage = (bf16*)smem;          // [128][136]
        #pragma unroll
        for (int mt = 0; mt < 4; ++mt)
            #pragma unroll
            for (int nt = 0; nt < 4; ++nt)
                #pragma unroll
                for (int r = 0; r < 4; ++r) {
                    int row = wm * 64 + mt * 16 + quad * 4 + r;
                    int col = wn * 64 + nt * 16 + ln15;
                    estage[row * 136 + col] =
                        __float2bfloat16(acc[mt][nt][r] + bias[nBase + col]);
                }
        __syncthreads();
        int row = tid >> 1, hf = tid & 1;
        #pragma unroll
        for (int j = 0; j < 4; ++j) {
            int col = hf * 64 + j * 16;
            *(uint4*)(Cb + (size_t)(mBase + row) * N + nBase + col) =
                *(const uint4*)&estage[row * 136 + col];
            *(uint4*)(Cb + (size_t)(mBase + row) * N + nBase + col + 8) =
                *(const uint4*)&estage[row * 136 + col + 8];
        }
        return;
    }

    if (mode == 2) {
        float* fstage = (float*)smem;        // [64][132]
        #pragma unroll
        for (int hf = 0; hf < 2; ++hf) {
            if (wm == hf) {
                #pragma unroll
                for (int mt = 0; mt < 4; ++mt)
                    #pragma unroll
                    for (int nt = 0; nt < 4; ++nt)
                        #pragma unroll
                        for (int r = 0; r < 4; ++r) {
                            int ml = mt * 16 + quad * 4 + r;
                            int col = wn * 64 + nt * 16 + ln15;
                            fstage[ml * 132 + col] = acc[mt][nt][r] + bias[col];
                        }
            }
            __syncthreads();
            int tl = tid >> 2, part = tid & 3;
            int g = mBase + hf * 64 + tl;
            int n_ = g & 63, w = (g >> 6) & 511, b = g >> 15;
            int ih = n_ >> 4, iw = (n_ >> 2) & 3, it = n_ & 3;
            int wh = w >> 6, ww = (w >> 3) & 7, wt = w & 7;
            int h  = (wh * 4 + ih + shift) & 31;
            int w2 = (ww * 4 + iw + shift) & 31;
            int t  = (wt * 4 + it + shift) & 31;
            size_t tok = ((size_t)b << 15) + ((h * 32 + w2) * 32 + t);
            float* dst = aux + tok * 128 + part * 32;
            #pragma unroll
            for (int j = 0; j < 8; ++j) {
                float4 a = *(float4*)(dst + j * 4);
                float4 l = *(const float4*)&fstage[tl * 132 + part * 32 + j * 4];
                a.x += l.x; a.y += l.y; a.z += l.z; a.w += l.w;
                *(float4*)(dst + j * 4) = a;
            }
            __syncthreads();
        }
        return;
    }

    // mode 5: BN + ReLU + transposed store
    {
        float* fstage = (float*)smem;        // [64 nn][132 sp]
        int b = mBase >> 15, sp0 = mBase & 32767;
        #pragma unroll
        for (int hf = 0; hf < 2; ++hf) {
            if (wn == hf) {
                #pragma unroll
                for (int nt = 0; nt < 4; ++nt) {
                    int ncol = nt * 16 + ln15;
                    int nn = nBase + hf * 64 + ncol;
                    float mean = aux[nn] * (1.0f / 65536.0f);
                    float var  = aux[256 + nn] * (1.0f / 65536.0f) - mean * mean;
                    float sc = rsqrtf(var + 1e-5f) * p1[nn];
                    float off = p2[nn] + bias[nn] * sc - mean * sc;
                    #pragma unroll
                    for (int mt = 0; mt < 4; ++mt)
                        #pragma unroll
                        for (int r = 0; r < 4; ++r) {
                            int ml = wm * 64 + mt * 16 + quad * 4 + r;
                            float y = acc[mt][nt][r] * sc + off;
                            fstage[ncol * 132 + ml] = fmaxf(y, 0.f);
                        }
                }
            }
            __syncthreads();
            int nl = tid >> 2, part = tid & 3;
            int nn = nBase + hf * 64 + nl;
            float* dst = Cf + (((size_t)(b * 256 + nn)) << 15) + sp0 + part * 32;
            #pragma unroll
            for (int j = 0; j < 8; ++j)
                *(float4*)(dst + j * 4) = *(const float4*)&fstage[nl * 132 + part * 32 + j * 4];
            __syncthreads();
        }
    }
}

// ---------------------------------------------------------------------------
// Fused MLP: LN2 + fc1(128->512) + GELU + fc2(512->128) + residual.
// One block per 64 tokens; 256 threads = 4 waves. Hidden kept in LDS.
// ---------------------------------------------------------------------------
__global__ __launch_bounds__(256) void mlp_kernel(
    float* __restrict__ xbuf, const float* __restrict__ g, const float* __restrict__ bta,
    const bf16* __restrict__ w1, const float* __restrict__ b1,
    const bf16* __restrict__ w2, const float* __restrict__ b2,
    bf16* __restrict__ xout16)
{
    __shared__ __align__(16) float xf[64 * 128];     // 32 KB fp32 residual copy
    __shared__ __align__(16) bf16  aln[64 * 136];    // 17 KB LN output
    __shared__ __align__(16) bf16  hid[64 * 520];    // 65 KB hidden
    int tid = threadIdx.x;
    int lane = tid & 63, wv = tid >> 6;
    int ln15 = lane & 15, quad = lane >> 4;
    int q8 = quad * 8;
    size_t tok0 = (size_t)blockIdx.x * 64;

    // load x fp32 -> LDS
    #pragma unroll
    for (int j = 0; j < 8; ++j) {
        int off = tid * 32 + j * 4;
        *(float4*)&xf[off] = *(const float4*)(xbuf + tok0 * 128 + off);
    }
    __syncthreads();

    // LayerNorm: wave wv handles tokens wv*16..wv*16+15
    for (int itk = 0; itk < 16; ++itk) {
        int t = wv * 16 + itk;
        float v0 = xf[t * 128 + lane], v1 = xf[t * 128 + lane + 64];
        float s = v0 + v1, sq = v0 * v0 + v1 * v1;
        #pragma unroll
        for (int o = 32; o > 0; o >>= 1) { s += __shfl_xor(s, o); sq += __shfl_xor(sq, o); }
        float mu  = s * (1.0f / 128.0f);
        float var = sq * (1.0f / 128.0f) - mu * mu;
        float rs  = rsqrtf(var + 1e-5f);
        aln[t * 136 + lane]      = __float2bfloat16((v0 - mu) * rs * g[lane]      + bta[lane]);
        aln[t * 136 + lane + 64] = __float2bfloat16((v1 - mu) * rs * g[lane + 64] + bta[lane + 64]);
    }
    __syncthreads();

    // fc1 + GELU: out [64, 512]; wave wv covers cols wv*128..wv*128+127 (2 passes of 64)
    #pragma unroll
    for (int np = 0; np < 2; ++np) {
        int nbase = wv * 128 + np * 64;
        floatx4 acc[4][4] = {};
        #pragma unroll
        for (int k0 = 0; k0 < 128; k0 += 32) {
            short8 af[4], bfr[4];
            #pragma unroll
            for (int mt = 0; mt < 4; ++mt)
                af[mt] = *(const short8*)&aln[(mt * 16 + ln15) * 136 + k0 + q8];
            #pragma unroll
            for (int nt = 0; nt < 4; ++nt)
                bfr[nt] = *(const short8*)(w1 + (size_t)(nbase + nt * 16 + ln15) * 128 + k0 + q8);
            #pragma unroll
            for (int mt = 0; mt < 4; ++mt)
                #pragma unroll
                for (int nt = 0; nt < 4; ++nt)
                    acc[mt][nt] = __builtin_amdgcn_mfma_f32_16x16x32_bf16(
                        af[mt], bfr[nt], acc[mt][nt], 0, 0, 0);
        }
        #pragma unroll
        for (int mt = 0; mt < 4; ++mt)
            #pragma unroll
            for (int nt = 0; nt < 4; ++nt)
                #pragma unroll
                for (int r = 0; r < 4; ++r) {
                    int m = mt * 16 + quad * 4 + r;
                    int n = nbase + nt * 16 + ln15;
                    float v = acc[mt][nt][r] + b1[n];
                    v = 0.5f * v * (1.0f + erff(v * 0.70710678118654752f));
                    hid[m * 520 + n] = __float2bfloat16(v);
                }
    }
    __syncthreads();

    // fc2: out [64, 128]; wave wv covers cols wv*32..wv*32+31
    floatx4 acc2[4][2] = {};
    for (int k0 = 0; k0 < 512; k0 += 32) {
        short8 af[4], bfr[2];
        #pragma unroll
        for (int mt = 0; mt < 4; ++mt)
            af[mt] = *(const short8*)&hid[(mt * 16 + ln15) * 520 + k0 + q8];
        #pragma unroll
        for (int nt = 0; nt < 2; ++nt)
            bfr[nt] = *(const short8*)(w2 + (size_t)(wv * 32 + nt * 16 + ln15) * 512 + k0 + q8);
        #pragma unroll
        for (int mt = 0; mt < 4; ++mt)
            #pragma unroll
            for (int nt = 0; nt < 2; ++nt)
                acc2[mt][nt] = __builtin_amdgcn_mfma_f32_16x16x32_bf16(
                    af[mt], bfr[nt], acc2[mt][nt], 0, 0, 0);
    }
    // residual add into xf
    #pragma unroll
    for (int mt = 0; mt < 4; ++mt)
        #pragma unroll
        for (int nt = 0; nt < 2; ++nt)
            #pragma unroll
            for (int r = 0; r < 4; ++r) {
                int m = mt * 16 + quad * 4 + r;
                int n = wv * 32 + nt * 16 + ln15;
                xf[m * 128 + n] += acc2[mt][nt][r] + b2[n];
            }
    __syncthreads();

    // coalesced store (fp32 always; bf16 copy if requested)
    #pragma unroll
    for (int j = 0; j < 8; ++j) {
        int off = tid * 32 + j * 4;
        float4 v = *(const float4*)&xf[off];
        *(float4*)(xbuf + tok0 * 128 + off) = v;
        if (xout16) {
            __align__(8) bf16 h[4];
            h[0] = __float2bfloat16(v.x); h[1] = __float2bfloat16(v.y);
            h[2] = __float2bfloat16(v.z); h[3] = __float2bfloat16(v.w);
            *(uint2*)(xout16 + tok0 * 128 + off) = *(const uint2*)h;
        }
    }
}

// ---------------------------------------------------------------------------
// Windowed attention (bf16 in/out): one block per (global window, head).
// ---------------------------------------------------------------------------
__global__ __launch_bounds__(64) void attn_kernel(
    const bf16* __restrict__ qkv, const float* __restrict__ rpb,
    bf16* __restrict__ outp, int shift)
{
    __shared__ float kt[64][16];
    __shared__ float vt[64][16];
    __shared__ float rp[343];
    __shared__ int   cnt[64];
    int blk = blockIdx.x;
    int head = blk & 7;
    int lw = blk >> 3;
    int i = threadIdx.x;
    const bf16* base = qkv + (size_t)(lw * 64) * 384 + head * 16;
    float q[16];
    #pragma unroll
    for (int d = 0; d < 16; ++d) q[d] = __bfloat162float(base[(size_t)i * 384 + d]) * 0.25f;
    #pragma unroll
    for (int d = 0; d < 16; ++d) kt[i][d] = __bfloat162float(base[(size_t)i * 384 + 128 + d]);
    #pragma unroll
    for (int d = 0; d < 16; ++d) vt[i][d] = __bfloat162float(base[(size_t)i * 384 + 256 + d]);
    for (int j = i; j < 343; j += 64) rp[j] = rpb[(size_t)j * 8 + head];
    int w = lw & 511;
    int ih = i >> 4, iw = (i >> 2) & 3, it = i & 3;
    if (shift) {
        int wh = w >> 6, ww = (w >> 3) & 7, wt = w & 7;
        int h = wh * 4 + ih, w2 = ww * 4 + iw, t = wt * 4 + it;
        int rh = (h  < 28) ? 0 : ((h  < 30) ? 1 : 2);
        int rw = (w2 < 28) ? 0 : ((w2 < 30) ? 1 : 2);
        int rt = (t  < 28) ? 0 : ((t  < 30) ? 1 : 2);
        cnt[i] = (rh * 3 + rw) * 3 + rt;
    }
    __syncthreads();
    float logits[64];
    int ci = shift ? cnt[i] : 0;
    #pragma unroll
    for (int j = 0; j < 64; ++j) {
        float d0 = 0.f;
        #pragma unroll
        for (int d = 0; d < 16; ++d) d0 += q[d] * kt[j][d];
        int jh = j >> 4, jw = (j >> 2) & 3, jt = j & 3;
        int ridx = ((ih - jh + 3) * 7 + (iw - jw + 3)) * 7 + (it - jt + 3);
        d0 += rp[ridx];
        if (shift && cnt[j] != ci) d0 -= 100.0f;
        logits[j] = d0;
    }
    float mx = -1e30f;
    #pragma unroll
    for (int j = 0; j < 64; ++j) mx = fmaxf(mx, logits[j]);
    float ssum = 0.f;
    #pragma unroll
    for (int j = 0; j < 64; ++j) { float e = __expf(logits[j] - mx); logits[j] = e; ssum += e; }
    float inv = 1.0f / ssum;
    float o[16] = {};
    #pragma unroll
    for (int j = 0; j < 64; ++j) {
        float p = logits[j] * inv;
        #pragma unroll
        for (int d = 0; d < 16; ++d) o[d] += p * vt[j][d];
    }
    bf16* op = outp + (size_t)(lw * 64 + i) * 128 + head * 16;
    #pragma unroll
    for (int d = 0; d < 16; ++d) op[d] = __float2bfloat16(o[d]);
}

// ---------------------------------------------------------------------------
// Depthwise 3x3x3 conv, bf16 in/out, register t-window reuse.
// ---------------------------------------------------------------------------
__global__ __launch_bounds__(512) void dwconv_kernel(
    const bf16* __restrict__ x, const float* __restrict__ dwt,
    const float* __restrict__ bias, bf16* __restrict__ out)
{
    int blk = blockIdx.x;
    int b = blk >> 10;
    int h = (blk >> 5) & 31;
    int w = blk & 31;
    int tid = threadIdx.x;
    int c = tid & 127;
    int t0 = (tid >> 7) * 8;
    float acc[8];
    float bs = bias[c];
    #pragma unroll
    for (int o = 0; o < 8; ++o) acc[o] = bs;
    #pragma unroll
    for (int kh = 0; kh < 3; ++kh) {
        int hh = h + kh - 1;
        if (hh < 0 || hh > 31) continue;
        #pragma unroll
        for (int kw = 0; kw < 3; ++kw) {
            int ww = w + kw - 1;
            if (ww < 0 || ww > 31) continue;
            const bf16* px = x + (((size_t)(b << 15) + (hh * 32 + ww) * 32) * 128) + c;
            float v[10];
            #pragma unroll
            for (int u = 0; u < 10; ++u) {
                int tt = t0 - 1 + u;
                v[u] = (tt >= 0 && tt < 32) ? __bfloat162float(px[(size_t)tt * 128]) : 0.f;
            }
            float w0 = dwt[((kh * 3 + kw) * 3 + 0) * 128 + c];
            float w1 = dwt[((kh * 3 + kw) * 3 + 1) * 128 + c];
            float w2 = dwt[((kh * 3 + kw) * 3 + 2) * 128 + c];
            #pragma unroll
            for (int o = 0; o < 8; ++o)
                acc[o] += v[o] * w0 + v[o + 1] * w1 + v[o + 2] * w2;
        }
    }
    bf16* po = out + (((size_t)(b << 15) + (h * 32 + w) * 32 + t0) * 128) + c;
    #pragma unroll
    for (int o = 0; o < 8; ++o) po[(size_t)o * 128] = __float2bfloat16(acc[o]);
}

// ---------------------------------------------------------------------------
extern "C" void kernel_launch(void* const* d_in, const int* in_sizes, int n_in,
                              void* d_out, int out_size, void* d_ws, size_t ws_size,
                              hipStream_t stream)
{
    const float* x_in    = (const float*)d_in[0];
    const float* norm1_g = (const float*)d_in[1];
    const float* norm1_b = (const float*)d_in[2];
    const float* qkv_w   = (const float*)d_in[3];
    const float* qkv_b   = (const float*)d_in[4];
    const float* proj_w  = (const float*)d_in[5];
    const float* proj_b  = (const float*)d_in[6];
    const float* rpb     = (const float*)d_in[7];
    const float* norm2_g = (const float*)d_in[8];
    const float* norm2_b = (const float*)d_in[9];
    const float* fc1_w   = (const float*)d_in[10];
    const float* fc1_b   = (const float*)d_in[11];
    const float* fc2_w   = (const float*)d_in[12];
    const float* fc2_b   = (const float*)d_in[13];
    const float* dw_w    = (const float*)d_in[14];
    const float* dw_b    = (const float*)d_in[15];
    const float* pw_w    = (const float*)d_in[16];
    const float* pw_b    = (const float*)d_in[17];
    const float* bn_g    = (const float*)d_in[18];
    const float* bn_b    = (const float*)d_in[19];
    float* out = (float*)d_out;

    char* ws = (char*)d_ws;
    float* xbuf   = (float*)ws;                          // [0,32MB)   fp32 [TOK,128]
    bf16*  wbf    = (bf16*)(ws + 33554432ULL);           // [32,34MB)  bf16 weights
    float* dwt    = (float*)(ws + 35651584ULL);          // 27x128 fp32
    float* stats  = (float*)(ws + 35651584ULL + 65536);  // 2 KB
    bf16*  lnbuf  = (bf16*)(ws + 37748736ULL);           // [36,52MB)  [TOK,128]
    bf16*  attnbuf= (bf16*)(ws + 54525952ULL);           // [52,68MB)  [TOK,128] (also dwbuf)
    bf16*  qkvbuf = (bf16*)(ws + 71303168ULL);           // [68,116MB) [TOK,384]
    bf16*  dwbuf  = attnbuf;
    bf16*  dcbuf  = lnbuf;

    bf16* wqkv  = wbf;                 // 4 x 384 x 128
    bf16* wproj = wbf + 196608;        // 4 x 128 x 128
    bf16* wfc1  = wbf + 262144;        // 4 x 512 x 128
    bf16* wfc2  = wbf + 524288;        // 4 x 128 x 512
    bf16* wpw   = wbf + 786432;        // 256 x 128

    hipLaunchKernelGGL(prep_kernel, dim3(3200), dim3(256), 0, stream,
                       qkv_w, proj_w, fc1_w, fc2_w, pw_w, dw_w, wbf, dwt, stats);
    hipLaunchKernelGGL(transpose_in_kernel, dim3(1024), dim3(256), 0, stream, x_in, xbuf);

    const int shifts[4] = {0, 2, 0, 2};
    for (int i = 0; i < 4; ++i) {
        int s = shifts[i];
        // --- attention half ---
        hipLaunchKernelGGL(ln_window_kernel, dim3(TOK / 4), dim3(256), 0, stream,
                           xbuf, lnbuf, norm1_g + i * 128, norm1_b + i * 128, s);
        hipLaunchKernelGGL(gemm_bf16_kernel, dim3(3, TOK / 128), dim3(256), 0, stream,
                           lnbuf, wqkv + (size_t)i * 49152, qkv_b + i * 384,
                           qkvbuf, (float*)nullptr, (float*)nullptr,
                           (const float*)nullptr, (const float*)nullptr,
                           TOK, 384, 128, 0, 0);
        hipLaunchKernelGGL(attn_kernel, dim3(1024 * HEADS), dim3(64), 0, stream,
                           qkvbuf, rpb + (size_t)i * 343 * 8, attnbuf, s);
        hipLaunchKernelGGL(gemm_bf16_kernel, dim3(1, TOK / 128), dim3(256), 0, stream,
                           attnbuf, wproj + (size_t)i * 16384, proj_b + i * 128,
                           (bf16*)nullptr, (float*)nullptr, xbuf,
                           (const float*)nullptr, (const float*)nullptr,
                           TOK, 128, 128, 2, s);
        // --- fused MLP ---
        hipLaunchKernelGGL(mlp_kernel, dim3(TOK / 64), dim3(256), 0, stream,
                           xbuf, norm2_g + i * 128, norm2_b + i * 128,
                           wfc1 + (size_t)i * 65536, fc1_b + i * 512,
                           wfc2 + (size_t)i * 65536, fc2_b + i * 128,
                           (i == 3) ? dwbuf : (bf16*)nullptr);
    }

    // connectBlock
    hipLaunchKernelGGL(dwconv_kernel, dim3(2048), dim3(512), 0, stream,
                       dwbuf, dwt, dw_b, dcbuf);
    hipLaunchKernelGGL(gemm_bf16_kernel, dim3(OUTC / 128, TOK / 128), dim3(256), 0, stream,
                       dcbuf, wpw, pw_b,
                       (bf16*)nullptr, (float*)nullptr, stats,
                       (const float*)nullptr, (const float*)nullptr,
                       TOK, OUTC, 128, 4, 0);
    hipLaunchKernelGGL(gemm_bf16_kernel, dim3(OUTC / 128, TOK / 128), dim3(256), 0, stream,
                       dcbuf, wpw, pw_b,
                       (bf16*)nullptr, out, stats,
                       bn_g, bn_b,
                       TOK, OUTC, 128, 5, 0);
}

// Round 6
// 1088.152 us; speedup vs baseline: 4.1085x; 1.0846x over previous
//
#include <hip/hip_runtime.h>
#include <hip/hip_bf16.h>
#include <cstddef>
#include <cstdint>

typedef __attribute__((ext_vector_type(8))) short short8;
typedef __attribute__((ext_vector_type(4))) float floatx4;
typedef __hip_bfloat16 bf16;

#define HEADS 8
#define TOK   65536
#define OUTC  256

// ---------------------------------------------------------------------------
// Transpose input (B,C,32,32,32) -> token-major xbuf[(b*32768+sp)*128 + c]
// ---------------------------------------------------------------------------
__global__ __launch_bounds__(256) void transpose_in_kernel(
    const float* __restrict__ x, float* __restrict__ out)
{
    __shared__ float tile[128 * 65];
    int chunk = blockIdx.x;
    int tid = threadIdx.x;
    int b = chunk >> 9;
    int sp0 = (chunk & 511) * 64;
    #pragma unroll
    for (int l = 0; l < 32; ++l) {
        int idx = l * 256 + tid;
        int c = idx >> 6;
        int s = idx & 63;
        tile[c * 65 + s] = x[(((size_t)(b * 128 + c)) << 15) + sp0 + s];
    }
    __syncthreads();
    #pragma unroll
    for (int l = 0; l < 32; ++l) {
        int idx = l * 256 + tid;
        int s = idx >> 7;
        int c = idx & 127;
        out[((size_t)((b << 15) + sp0 + s)) * 128 + c] = tile[c * 65 + s];
    }
}

// ---------------------------------------------------------------------------
// Prep: weight fp32->bf16 conversions + dw-weight transpose + stats zero.
// ---------------------------------------------------------------------------
__global__ __launch_bounds__(256) void prep_kernel(
    const float* __restrict__ qkv_w, const float* __restrict__ proj_w,
    const float* __restrict__ fc1_w, const float* __restrict__ fc2_w,
    const float* __restrict__ pw_w, const float* __restrict__ dw_w,
    bf16* __restrict__ wbf, float* __restrict__ dwt, float* __restrict__ stats)
{
    int i = blockIdx.x * 256 + threadIdx.x;
    float v;
    if (i < 196608)       v = qkv_w[i];
    else if (i < 262144)  v = proj_w[i - 196608];
    else if (i < 524288)  v = fc1_w[i - 262144];
    else if (i < 786432)  v = fc2_w[i - 524288];
    else                  v = pw_w[i - 786432];
    wbf[i] = __float2bfloat16(v);
    if (i < 3456) {
        int c = i / 27, k = i % 27;
        dwt[k * 128 + c] = dw_w[i];
    }
    if (i < 512) stats[i] = 0.f;
}

// ---------------------------------------------------------------------------
// LayerNorm + cyclic shift + window partition -> bf16. 4 tokens per block.
// ---------------------------------------------------------------------------
__global__ __launch_bounds__(256) void ln_window_kernel(
    const float* __restrict__ x, bf16* __restrict__ out,
    const float* __restrict__ g, const float* __restrict__ bta, int shift)
{
    int m = blockIdx.x * 4 + (threadIdx.x >> 6);
    int lane = threadIdx.x & 63;
    int n = m & 63, w = (m >> 6) & 511, b = m >> 15;
    int ih = n >> 4, iw = (n >> 2) & 3, it = n & 3;
    int wh = w >> 6, ww = (w >> 3) & 7, wt = w & 7;
    int h  = (wh * 4 + ih + shift) & 31;
    int w2 = (ww * 4 + iw + shift) & 31;
    int t  = (wt * 4 + it + shift) & 31;
    size_t tok = ((size_t)b << 15) + ((h * 32 + w2) * 32 + t);
    const float* xp = x + tok * 128;
    float v0 = xp[lane], v1 = xp[lane + 64];
    float s = v0 + v1, sq = v0 * v0 + v1 * v1;
    #pragma unroll
    for (int o = 32; o > 0; o >>= 1) { s += __shfl_xor(s, o); sq += __shfl_xor(sq, o); }
    float mu  = s * (1.0f / 128.0f);
    float var = sq * (1.0f / 128.0f) - mu * mu;
    float rs  = rsqrtf(var + 1e-5f);
    bf16* op = out + (size_t)m * 128;
    op[lane]      = __float2bfloat16((v0 - mu) * rs * g[lane]      + bta[lane]);
    op[lane + 64] = __float2bfloat16((v1 - mu) * rs * g[lane + 64] + bta[lane + 64]);
}

// ---------------------------------------------------------------------------
// bf16 MFMA GEMM with coalesced LDS-staged epilogues.
// 128x128 tile, 256 threads = 4 waves (2x2 of 64x64), BK=32.
// mode 0: Cb[m*N+n] = bf16(v)                (LDS-staged row stores)
// mode 2: scatter-add (un-shift) into aux    (LDS-staged per-token f4 RMW)
// mode 4: BN stats: aux[n] += v, aux[256+n] += v^2
// mode 5: BN+ReLU+transpose to Cf            (LDS-transposed channel stores)
// ---------------------------------------------------------------------------
__global__ __launch_bounds__(256) void gemm_bf16_kernel(
    const bf16* __restrict__ A, const bf16* __restrict__ Bw,
    const float* __restrict__ bias, bf16* __restrict__ Cb, float* __restrict__ Cf,
    float* __restrict__ aux, const float* __restrict__ p1, const float* __restrict__ p2,
    int M, int N, int K, int mode, int shift)
{
    __shared__ __align__(16) char smem[34816];
    __shared__ float cs[128];
    __shared__ float cq[128];
    short* As = (short*)smem;
    short* Bs = (short*)(smem + 8192);
    int tid = threadIdx.x;
    int lane = tid & 63, wv = tid >> 6;
    int wm = wv >> 1, wn = wv & 1;
    int ln15 = lane & 15, quad = lane >> 4;
    int q8 = quad * 8;
    int nBase = blockIdx.x * 128;
    int mBase = blockIdx.y * 128;
    floatx4 acc[4][4] = {};

    if (mode == 4 && tid < 128) { cs[tid] = 0.f; cq[tid] = 0.f; }

    int srow = tid >> 2, scb = tid & 3;
    for (int k0 = 0; k0 < K; k0 += 32) {
        #pragma unroll
        for (int i = 0; i < 2; ++i) {
            int row = srow + i * 64;
            ((uint4*)As)[i * 256 + tid] =
                *(const uint4*)(A + (size_t)(mBase + row) * K + k0 + scb * 8);
            ((uint4*)Bs)[i * 256 + tid] =
                *(const uint4*)(Bw + (size_t)(nBase + row) * K + k0 + scb * 8);
        }
        __syncthreads();
        short8 af[4], bfr[4];
        #pragma unroll
        for (int mt = 0; mt < 4; ++mt)
            af[mt] = *(const short8*)&As[(wm * 64 + mt * 16 + ln15) * 32 + q8];
        #pragma unroll
        for (int nt = 0; nt < 4; ++nt)
            bfr[nt] = *(const short8*)&Bs[(wn * 64 + nt * 16 + ln15) * 32 + q8];
        #pragma unroll
        for (int mt = 0; mt < 4; ++mt)
            #pragma unroll
            for (int nt = 0; nt < 4; ++nt)
                acc[mt][nt] = __builtin_amdgcn_mfma_f32_16x16x32_bf16(
                    af[mt], bfr[nt], acc[mt][nt], 0, 0, 0);
        __syncthreads();
    }

    if (mode == 4) {
        #pragma unroll
        for (int nt = 0; nt < 4; ++nt) {
            int nl = wn * 64 + nt * 16 + ln15;
            float bs = bias[nBase + nl];
            float s = 0.f, sq = 0.f;
            #pragma unroll
            for (int mt = 0; mt < 4; ++mt)
                #pragma unroll
                for (int r = 0; r < 4; ++r) {
                    float v = acc[mt][nt][r] + bs;
                    s += v; sq += v * v;
                }
            atomicAdd(&cs[nl], s);
            atomicAdd(&cq[nl], sq);
        }
        __syncthreads();
        if (tid < 128) {
            atomicAdd(&aux[nBase + tid], cs[tid]);
            atomicAdd(&aux[256 + nBase + tid], cq[tid]);
        }
        return;
    }

    if (mode == 0) {
        bf16* estage = (bf16*)smem;          // [128][136]
        #pragma unroll
        for (int mt = 0; mt < 4; ++mt)
            #pragma unroll
            for (int nt = 0; nt < 4; ++nt)
                #pragma unroll
                for (int r = 0; r < 4; ++r) {
                    int row = wm * 64 + mt * 16 + quad * 4 + r;
                    int col = wn * 64 + nt * 16 + ln15;
                    estage[row * 136 + col] =
                        __float2bfloat16(acc[mt][nt][r] + bias[nBase + col]);
                }
        __syncthreads();
        int row = tid >> 1, hf = tid & 1;
        #pragma unroll
        for (int j = 0; j < 4; ++j) {
            int col = hf * 64 + j * 16;
            *(uint4*)(Cb + (size_t)(mBase + row) * N + nBase + col) =
                *(const uint4*)&estage[row * 136 + col];
            *(uint4*)(Cb + (size_t)(mBase + row) * N + nBase + col + 8) =
                *(const uint4*)&estage[row * 136 + col + 8];
        }
        return;
    }

    if (mode == 2) {
        float* fstage = (float*)smem;        // [64][132]
        #pragma unroll
        for (int hf = 0; hf < 2; ++hf) {
            if (wm == hf) {
                #pragma unroll
                for (int mt = 0; mt < 4; ++mt)
                    #pragma unroll
                    for (int nt = 0; nt < 4; ++nt)
                        #pragma unroll
                        for (int r = 0; r < 4; ++r) {
                            int ml = mt * 16 + quad * 4 + r;
                            int col = wn * 64 + nt * 16 + ln15;
                            fstage[ml * 132 + col] = acc[mt][nt][r] + bias[col];
                        }
            }
            __syncthreads();
            int tl = tid >> 2, part = tid & 3;
            int g = mBase + hf * 64 + tl;
            int n_ = g & 63, w = (g >> 6) & 511, b = g >> 15;
            int ih = n_ >> 4, iw = (n_ >> 2) & 3, it = n_ & 3;
            int wh = w >> 6, ww = (w >> 3) & 7, wt = w & 7;
            int h  = (wh * 4 + ih + shift) & 31;
            int w2 = (ww * 4 + iw + shift) & 31;
            int t  = (wt * 4 + it + shift) & 31;
            size_t tok = ((size_t)b << 15) + ((h * 32 + w2) * 32 + t);
            float* dst = aux + tok * 128 + part * 32;
            #pragma unroll
            for (int j = 0; j < 8; ++j) {
                float4 a = *(float4*)(dst + j * 4);
                float4 l = *(const float4*)&fstage[tl * 132 + part * 32 + j * 4];
                a.x += l.x; a.y += l.y; a.z += l.z; a.w += l.w;
                *(float4*)(dst + j * 4) = a;
            }
            __syncthreads();
        }
        return;
    }

    // mode 5: BN + ReLU + transposed store
    {
        float* fstage = (float*)smem;        // [64 nn][132 sp]
        int b = mBase >> 15, sp0 = mBase & 32767;
        #pragma unroll
        for (int hf = 0; hf < 2; ++hf) {
            if (wn == hf) {
                #pragma unroll
                for (int nt = 0; nt < 4; ++nt) {
                    int ncol = nt * 16 + ln15;
                    int nn = nBase + hf * 64 + ncol;
                    float mean = aux[nn] * (1.0f / 65536.0f);
                    float var  = aux[256 + nn] * (1.0f / 65536.0f) - mean * mean;
                    float sc = rsqrtf(var + 1e-5f) * p1[nn];
                    float off = p2[nn] + bias[nn] * sc - mean * sc;
                    #pragma unroll
                    for (int mt = 0; mt < 4; ++mt)
                        #pragma unroll
                        for (int r = 0; r < 4; ++r) {
                            int ml = wm * 64 + mt * 16 + quad * 4 + r;
                            float y = acc[mt][nt][r] * sc + off;
                            fstage[ncol * 132 + ml] = fmaxf(y, 0.f);
                        }
                }
            }
            __syncthreads();
            int nl = tid >> 2, part = tid & 3;
            int nn = nBase + hf * 64 + nl;
            float* dst = Cf + (((size_t)(b * 256 + nn)) << 15) + sp0 + part * 32;
            #pragma unroll
            for (int j = 0; j < 8; ++j)
                *(float4*)(dst + j * 4) = *(const float4*)&fstage[nl * 132 + part * 32 + j * 4];
            __syncthreads();
        }
    }
}

// ---------------------------------------------------------------------------
// Fused MLP v2: LN2 + fc1(128->512) + GELU + fc2(512->128) + residual.
// 32 tokens / block, 256 threads = 4 waves. LDS ~49 KB -> 3 blocks/CU.
// x re-read from global for residual (L2-warm); all global/LDS bulk moves
// use consecutive-lane float4 addressing.
// ---------------------------------------------------------------------------
__global__ __launch_bounds__(256) void mlp_kernel(
    float* __restrict__ xbuf, const float* __restrict__ g, const float* __restrict__ bta,
    const bf16* __restrict__ w1, const float* __restrict__ b1,
    const bf16* __restrict__ w2, const float* __restrict__ b2,
    bf16* __restrict__ xout16)
{
    __shared__ __align__(16) bf16  hid[32 * 520];            // 33.3 KB
    __shared__ __align__(16) char  un[32 * 132 * 4];         // 16.9 KB: aln / ostage
    bf16*  aln    = (bf16*)un;                                // [32][136]
    float* ostage = (float*)un;                               // [32][132]
    int tid = threadIdx.x;
    int lane = tid & 63, wv = tid >> 6;
    int ln15 = lane & 15, quad = lane >> 4;
    int q8 = quad * 8;
    size_t tok0 = (size_t)blockIdx.x * 32;

    // LayerNorm: wave wv handles tokens wv*8 .. wv*8+7, direct from global
    #pragma unroll
    for (int itk = 0; itk < 8; ++itk) {
        int t = wv * 8 + itk;
        const float* xp = xbuf + (tok0 + t) * 128;
        float v0 = xp[lane], v1 = xp[lane + 64];
        float s = v0 + v1, sq = v0 * v0 + v1 * v1;
        #pragma unroll
        for (int o = 32; o > 0; o >>= 1) { s += __shfl_xor(s, o); sq += __shfl_xor(sq, o); }
        float mu  = s * (1.0f / 128.0f);
        float var = sq * (1.0f / 128.0f) - mu * mu;
        float rs  = rsqrtf(var + 1e-5f);
        aln[t * 136 + lane]      = __float2bfloat16((v0 - mu) * rs * g[lane]      + bta[lane]);
        aln[t * 136 + lane + 64] = __float2bfloat16((v1 - mu) * rs * g[lane + 64] + bta[lane + 64]);
    }
    __syncthreads();

    // fc1 + GELU: out [32, 512]; wave wv covers cols wv*128..+127 (2 passes of 64)
    #pragma unroll
    for (int np = 0; np < 2; ++np) {
        int nbase = wv * 128 + np * 64;
        floatx4 acc[2][4] = {};
        #pragma unroll
        for (int k0 = 0; k0 < 128; k0 += 32) {
            short8 af[2], bfr[4];
            #pragma unroll
            for (int mt = 0; mt < 2; ++mt)
                af[mt] = *(const short8*)&aln[(mt * 16 + ln15) * 136 + k0 + q8];
            #pragma unroll
            for (int nt = 0; nt < 4; ++nt)
                bfr[nt] = *(const short8*)(w1 + (size_t)(nbase + nt * 16 + ln15) * 128 + k0 + q8);
            #pragma unroll
            for (int mt = 0; mt < 2; ++mt)
                #pragma unroll
                for (int nt = 0; nt < 4; ++nt)
                    acc[mt][nt] = __builtin_amdgcn_mfma_f32_16x16x32_bf16(
                        af[mt], bfr[nt], acc[mt][nt], 0, 0, 0);
        }
        #pragma unroll
        for (int mt = 0; mt < 2; ++mt)
            #pragma unroll
            for (int nt = 0; nt < 4; ++nt)
                #pragma unroll
                for (int r = 0; r < 4; ++r) {
                    int m = mt * 16 + quad * 4 + r;
                    int n = nbase + nt * 16 + ln15;
                    float v = acc[mt][nt][r] + b1[n];
                    v = 0.5f * v * (1.0f + erff(v * 0.70710678118654752f));
                    hid[m * 520 + n] = __float2bfloat16(v);
                }
    }
    __syncthreads();   // hid complete; aln dead -> un region reusable

    // fc2: out [32, 128]; wave wv covers cols wv*32..+31
    floatx4 acc2[2][2] = {};
    for (int k0 = 0; k0 < 512; k0 += 32) {
        short8 af[2], bfr[2];
        #pragma unroll
        for (int mt = 0; mt < 2; ++mt)
            af[mt] = *(const short8*)&hid[(mt * 16 + ln15) * 520 + k0 + q8];
        #pragma unroll
        for (int nt = 0; nt < 2; ++nt)
            bfr[nt] = *(const short8*)(w2 + (size_t)(wv * 32 + nt * 16 + ln15) * 512 + k0 + q8);
        #pragma unroll
        for (int mt = 0; mt < 2; ++mt)
            #pragma unroll
            for (int nt = 0; nt < 2; ++nt)
                acc2[mt][nt] = __builtin_amdgcn_mfma_f32_16x16x32_bf16(
                    af[mt], bfr[nt], acc2[mt][nt], 0, 0, 0);
    }
    // stage fc2 output (with bias) into ostage
    #pragma unroll
    for (int mt = 0; mt < 2; ++mt)
        #pragma unroll
        for (int nt = 0; nt < 2; ++nt)
            #pragma unroll
            for (int r = 0; r < 4; ++r) {
                int m = mt * 16 + quad * 4 + r;
                int n = wv * 32 + nt * 16 + ln15;
                ostage[m * 132 + n] = acc2[mt][nt][r] + b2[n];
            }
    __syncthreads();

    // residual: read x (global, L2-warm), add, store; consecutive-lane float4
    #pragma unroll
    for (int j = 0; j < 4; ++j) {
        int idx = (j * 256 + tid) * 4;          // 0..4095 floats
        int t = idx >> 7, c = idx & 127;
        float4 v = *(const float4*)(xbuf + tok0 * 128 + idx);
        float4 o = *(const float4*)&ostage[t * 132 + c];
        v.x += o.x; v.y += o.y; v.z += o.z; v.w += o.w;
        *(float4*)(xbuf + tok0 * 128 + idx) = v;
        if (xout16) {
            __align__(8) bf16 hh[4];
            hh[0] = __float2bfloat16(v.x); hh[1] = __float2bfloat16(v.y);
            hh[2] = __float2bfloat16(v.z); hh[3] = __float2bfloat16(v.w);
            *(uint2*)(xout16 + tok0 * 128 + idx) = *(const uint2*)hh;
        }
    }
}

// ---------------------------------------------------------------------------
// Windowed attention (bf16 in/out): one block per (global window, head).
// ---------------------------------------------------------------------------
__global__ __launch_bounds__(64) void attn_kernel(
    const bf16* __restrict__ qkv, const float* __restrict__ rpb,
    bf16* __restrict__ outp, int shift)
{
    __shared__ float kt[64][16];
    __shared__ float vt[64][16];
    __shared__ float rp[343];
    __shared__ int   cnt[64];
    int blk = blockIdx.x;
    int head = blk & 7;
    int lw = blk >> 3;
    int i = threadIdx.x;
    const bf16* base = qkv + (size_t)(lw * 64) * 384 + head * 16;
    float q[16];
    #pragma unroll
    for (int d = 0; d < 16; ++d) q[d] = __bfloat162float(base[(size_t)i * 384 + d]) * 0.25f;
    #pragma unroll
    for (int d = 0; d < 16; ++d) kt[i][d] = __bfloat162float(base[(size_t)i * 384 + 128 + d]);
    #pragma unroll
    for (int d = 0; d < 16; ++d) vt[i][d] = __bfloat162float(base[(size_t)i * 384 + 256 + d]);
    for (int j = i; j < 343; j += 64) rp[j] = rpb[(size_t)j * 8 + head];
    int w = lw & 511;
    int ih = i >> 4, iw = (i >> 2) & 3, it = i & 3;
    if (shift) {
        int wh = w >> 6, ww = (w >> 3) & 7, wt = w & 7;
        int h = wh * 4 + ih, w2 = ww * 4 + iw, t = wt * 4 + it;
        int rh = (h  < 28) ? 0 : ((h  < 30) ? 1 : 2);
        int rw = (w2 < 28) ? 0 : ((w2 < 30) ? 1 : 2);
        int rt = (t  < 28) ? 0 : ((t  < 30) ? 1 : 2);
        cnt[i] = (rh * 3 + rw) * 3 + rt;
    }
    __syncthreads();
    float logits[64];
    int ci = shift ? cnt[i] : 0;
    #pragma unroll
    for (int j = 0; j < 64; ++j) {
        float d0 = 0.f;
        #pragma unroll
        for (int d = 0; d < 16; ++d) d0 += q[d] * kt[j][d];
        int jh = j >> 4, jw = (j >> 2) & 3, jt = j & 3;
        int ridx = ((ih - jh + 3) * 7 + (iw - jw + 3)) * 7 + (it - jt + 3);
        d0 += rp[ridx];
        if (shift && cnt[j] != ci) d0 -= 100.0f;
        logits[j] = d0;
    }
    float mx = -1e30f;
    #pragma unroll
    for (int j = 0; j < 64; ++j) mx = fmaxf(mx, logits[j]);
    float ssum = 0.f;
    #pragma unroll
    for (int j = 0; j < 64; ++j) { float e = __expf(logits[j] - mx); logits[j] = e; ssum += e; }
    float inv = 1.0f / ssum;
    float o[16] = {};
    #pragma unroll
    for (int j = 0; j < 64; ++j) {
        float p = logits[j] * inv;
        #pragma unroll
        for (int d = 0; d < 16; ++d) o[d] += p * vt[j][d];
    }
    bf16* op = outp + (size_t)(lw * 64 + i) * 128 + head * 16;
    #pragma unroll
    for (int d = 0; d < 16; ++d) op[d] = __float2bfloat16(o[d]);
}

// ---------------------------------------------------------------------------
// Depthwise 3x3x3 conv, bf16 in/out, register t-window reuse.
// ---------------------------------------------------------------------------
__global__ __launch_bounds__(512) void dwconv_kernel(
    const bf16* __restrict__ x, const float* __restrict__ dwt,
    const float* __restrict__ bias, bf16* __restrict__ out)
{
    int blk = blockIdx.x;
    int b = blk >> 10;
    int h = (blk >> 5) & 31;
    int w = blk & 31;
    int tid = threadIdx.x;
    int c = tid & 127;
    int t0 = (tid >> 7) * 8;
    float acc[8];
    float bs = bias[c];
    #pragma unroll
    for (int o = 0; o < 8; ++o) acc[o] = bs;
    #pragma unroll
    for (int kh = 0; kh < 3; ++kh) {
        int hh = h + kh - 1;
        if (hh < 0 || hh > 31) continue;
        #pragma unroll
        for (int kw = 0; kw < 3; ++kw) {
            int ww = w + kw - 1;
            if (ww < 0 || ww > 31) continue;
            const bf16* px = x + (((size_t)(b << 15) + (hh * 32 + ww) * 32) * 128) + c;
            float v[10];
            #pragma unroll
            for (int u = 0; u < 10; ++u) {
                int tt = t0 - 1 + u;
                v[u] = (tt >= 0 && tt < 32) ? __bfloat162float(px[(size_t)tt * 128]) : 0.f;
            }
            float w0 = dwt[((kh * 3 + kw) * 3 + 0) * 128 + c];
            float w1 = dwt[((kh * 3 + kw) * 3 + 1) * 128 + c];
            float w2 = dwt[((kh * 3 + kw) * 3 + 2) * 128 + c];
            #pragma unroll
            for (int o = 0; o < 8; ++o)
                acc[o] += v[o] * w0 + v[o + 1] * w1 + v[o + 2] * w2;
        }
    }
    bf16* po = out + (((size_t)(b << 15) + (h * 32 + w) * 32 + t0) * 128) + c;
    #pragma unroll
    for (int o = 0; o < 8; ++o) po[(size_t)o * 128] = __float2bfloat16(acc[o]);
}

// ---------------------------------------------------------------------------
extern "C" void kernel_launch(void* const* d_in, const int* in_sizes, int n_in,
                              void* d_out, int out_size, void* d_ws, size_t ws_size,
                              hipStream_t stream)
{
    const float* x_in    = (const float*)d_in[0];
    const float* norm1_g = (const float*)d_in[1];
    const float* norm1_b = (const float*)d_in[2];
    const float* qkv_w   = (const float*)d_in[3];
    const float* qkv_b   = (const float*)d_in[4];
    const float* proj_w  = (const float*)d_in[5];
    const float* proj_b  = (const float*)d_in[6];
    const float* rpb     = (const float*)d_in[7];
    const float* norm2_g = (const float*)d_in[8];
    const float* norm2_b = (const float*)d_in[9];
    const float* fc1_w   = (const float*)d_in[10];
    const float* fc1_b   = (const float*)d_in[11];
    const float* fc2_w   = (const float*)d_in[12];
    const float* fc2_b   = (const float*)d_in[13];
    const float* dw_w    = (const float*)d_in[14];
    const float* dw_b    = (const float*)d_in[15];
    const float* pw_w    = (const float*)d_in[16];
    const float* pw_b    = (const float*)d_in[17];
    const float* bn_g    = (const float*)d_in[18];
    const float* bn_b    = (const float*)d_in[19];
    float* out = (float*)d_out;

    char* ws = (char*)d_ws;
    float* xbuf   = (float*)ws;                          // [0,32MB)   fp32 [TOK,128]
    bf16*  wbf    = (bf16*)(ws + 33554432ULL);           // [32,34MB)  bf16 weights
    float* dwt    = (float*)(ws + 35651584ULL);          // 27x128 fp32
    float* stats  = (float*)(ws + 35651584ULL + 65536);  // 2 KB
    bf16*  lnbuf  = (bf16*)(ws + 37748736ULL);           // [36,52MB)  [TOK,128]
    bf16*  attnbuf= (bf16*)(ws + 54525952ULL);           // [52,68MB)  [TOK,128] (also dwbuf)
    bf16*  qkvbuf = (bf16*)(ws + 71303168ULL);           // [68,116MB) [TOK,384]
    bf16*  dwbuf  = attnbuf;
    bf16*  dcbuf  = lnbuf;

    bf16* wqkv  = wbf;                 // 4 x 384 x 128
    bf16* wproj = wbf + 196608;        // 4 x 128 x 128
    bf16* wfc1  = wbf + 262144;        // 4 x 512 x 128
    bf16* wfc2  = wbf + 524288;        // 4 x 128 x 512
    bf16* wpw   = wbf + 786432;        // 256 x 128

    hipLaunchKernelGGL(prep_kernel, dim3(3200), dim3(256), 0, stream,
                       qkv_w, proj_w, fc1_w, fc2_w, pw_w, dw_w, wbf, dwt, stats);
    hipLaunchKernelGGL(transpose_in_kernel, dim3(1024), dim3(256), 0, stream, x_in, xbuf);

    const int shifts[4] = {0, 2, 0, 2};
    for (int i = 0; i < 4; ++i) {
        int s = shifts[i];
        // --- attention half ---
        hipLaunchKernelGGL(ln_window_kernel, dim3(TOK / 4), dim3(256), 0, stream,
                           xbuf, lnbuf, norm1_g + i * 128, norm1_b + i * 128, s);
        hipLaunchKernelGGL(gemm_bf16_kernel, dim3(3, TOK / 128), dim3(256), 0, stream,
                           lnbuf, wqkv + (size_t)i * 49152, qkv_b + i * 384,
                           qkvbuf, (float*)nullptr, (float*)nullptr,
                           (const float*)nullptr, (const float*)nullptr,
                           TOK, 384, 128, 0, 0);
        hipLaunchKernelGGL(attn_kernel, dim3(1024 * HEADS), dim3(64), 0, stream,
                           qkvbuf, rpb + (size_t)i * 343 * 8, attnbuf, s);
        hipLaunchKernelGGL(gemm_bf16_kernel, dim3(1, TOK / 128), dim3(256), 0, stream,
                           attnbuf, wproj + (size_t)i * 16384, proj_b + i * 128,
                           (bf16*)nullptr, (float*)nullptr, xbuf,
                           (const float*)nullptr, (const float*)nullptr,
                           TOK, 128, 128, 2, s);
        // --- fused MLP (32-token tiles) ---
        hipLaunchKernelGGL(mlp_kernel, dim3(TOK / 32), dim3(256), 0, stream,
                           xbuf, norm2_g + i * 128, norm2_b + i * 128,
                           wfc1 + (size_t)i * 65536, fc1_b + i * 512,
                           wfc2 + (size_t)i * 65536, fc2_b + i * 128,
                           (i == 3) ? dwbuf : (bf16*)nullptr);
    }

    // connectBlock
    hipLaunchKernelGGL(dwconv_kernel, dim3(2048), dim3(512), 0, stream,
                       dwbuf, dwt, dw_b, dcbuf);
    hipLaunchKernelGGL(gemm_bf16_kernel, dim3(OUTC / 128, TOK / 128), dim3(256), 0, stream,
                       dcbuf, wpw, pw_b,
                       (bf16*)nullptr, (float*)nullptr, stats,
                       (const float*)nullptr, (const float*)nullptr,
                       TOK, OUTC, 128, 4, 0);
    hipLaunchKernelGGL(gemm_bf16_kernel, dim3(OUTC / 128, TOK / 128), dim3(256), 0, stream,
                       dcbuf, wpw, pw_b,
                       (bf16*)nullptr, out, stats,
                       bn_g, bn_b,
                       TOK, OUTC, 128, 5, 0);
}

// Round 7
// 1005.893 us; speedup vs baseline: 4.4445x; 1.0818x over previous
//
#include <hip/hip_runtime.h>
#include <hip/hip_bf16.h>
#include <cstddef>
#include <cstdint>

typedef __attribute__((ext_vector_type(8))) short short8;
typedef __attribute__((ext_vector_type(4))) float floatx4;
typedef __hip_bfloat16 bf16;

#define HEADS 8
#define TOK   65536
#define OUTC  256

__device__ inline float b2f(short s) {
    union { unsigned u; float f; } x;
    x.u = ((unsigned)(unsigned short)s) << 16;
    return x.f;
}

// ---------------------------------------------------------------------------
// Transpose input (B,C,32,32,32) -> token-major xbuf[(b*32768+sp)*128 + c]
// ---------------------------------------------------------------------------
__global__ __launch_bounds__(256) void transpose_in_kernel(
    const float* __restrict__ x, float* __restrict__ out)
{
    __shared__ float tile[128 * 65];
    int chunk = blockIdx.x;
    int tid = threadIdx.x;
    int b = chunk >> 9;
    int sp0 = (chunk & 511) * 64;
    #pragma unroll
    for (int l = 0; l < 32; ++l) {
        int idx = l * 256 + tid;
        int c = idx >> 6;
        int s = idx & 63;
        tile[c * 65 + s] = x[(((size_t)(b * 128 + c)) << 15) + sp0 + s];
    }
    __syncthreads();
    #pragma unroll
    for (int l = 0; l < 32; ++l) {
        int idx = l * 256 + tid;
        int s = idx >> 7;
        int c = idx & 127;
        out[((size_t)((b << 15) + sp0 + s)) * 128 + c] = tile[c * 65 + s];
    }
}

// ---------------------------------------------------------------------------
// Prep: weight fp32->bf16 conversions + dw-weight transpose + stats zero.
// ---------------------------------------------------------------------------
__global__ __launch_bounds__(256) void prep_kernel(
    const float* __restrict__ qkv_w, const float* __restrict__ proj_w,
    const float* __restrict__ fc1_w, const float* __restrict__ fc2_w,
    const float* __restrict__ pw_w, const float* __restrict__ dw_w,
    bf16* __restrict__ wbf, float* __restrict__ dwt, float* __restrict__ stats)
{
    int i = blockIdx.x * 256 + threadIdx.x;
    float v;
    if (i < 196608)       v = qkv_w[i];
    else if (i < 262144)  v = proj_w[i - 196608];
    else if (i < 524288)  v = fc1_w[i - 262144];
    else if (i < 786432)  v = fc2_w[i - 524288];
    else                  v = pw_w[i - 786432];
    wbf[i] = __float2bfloat16(v);
    if (i < 3456) {
        int c = i / 27, k = i % 27;
        dwt[k * 128 + c] = dw_w[i];
    }
    if (i < 512) stats[i] = 0.f;
}

// ---------------------------------------------------------------------------
// Pack fc1/fc2 weights into MFMA-fragment order + transpose rpb head-major.
// pw1[i] flat idx: g(3b)|kk(2b)|nt(2b)|lane(6b)|j(3b) ->
//   fc1_w[row = g*64+nt*16+(lane&15)][col = kk*32+(lane>>4)*8+j]
// pw2[i] flat idx: wv(2b)|cc(1b)|ks(3b)|nt(1b)|lane(6b)|j(3b) ->
//   fc2_w[row = wv*32+nt*16+(lane&15)][col = cc*256+ks*32+(lane>>4)*8+j]
// grid = 2048 x 256
// ---------------------------------------------------------------------------
__global__ __launch_bounds__(256) void pack_kernel(
    const float* __restrict__ fc1_w, const float* __restrict__ fc2_w,
    const float* __restrict__ rpb,
    bf16* __restrict__ pw1, bf16* __restrict__ pw2, float* __restrict__ rpbt)
{
    int t = blockIdx.x * 256 + threadIdx.x;
    int i = t >> 17;
    int rem = t & 131071;
    int type = rem >> 16;
    int idx = rem & 65535;
    int j = idx & 7, lane = (idx >> 3) & 63;
    int ln15 = lane & 15, quad = lane >> 4;
    if (type == 0) {
        int nt = (idx >> 9) & 3, kk = (idx >> 11) & 3, g = (idx >> 13) & 7;
        int row = g * 64 + nt * 16 + ln15;
        int col = kk * 32 + quad * 8 + j;
        pw1[i * 65536 + idx] = __float2bfloat16(fc1_w[(size_t)i * 65536 + row * 128 + col]);
    } else {
        int nt = (idx >> 9) & 1, ks = (idx >> 10) & 7, cc = (idx >> 13) & 1, wv = (idx >> 14) & 3;
        int row = wv * 32 + nt * 16 + ln15;
        int col = cc * 256 + ks * 32 + quad * 8 + j;
        pw2[i * 65536 + idx] = __float2bfloat16(fc2_w[(size_t)i * 65536 + row * 512 + col]);
    }
    if (t < 10976) {
        int li = t / 2744, r = t - li * 2744;
        int head = r / 343, jj = r - head * 343;
        rpbt[t] = rpb[li * 2744 + jj * 8 + head];
    }
}

// ---------------------------------------------------------------------------
// LayerNorm + cyclic shift + window partition -> bf16. 4 tokens per block.
// ---------------------------------------------------------------------------
__global__ __launch_bounds__(256) void ln_window_kernel(
    const float* __restrict__ x, bf16* __restrict__ out,
    const float* __restrict__ g, const float* __restrict__ bta, int shift)
{
    int m = blockIdx.x * 4 + (threadIdx.x >> 6);
    int lane = threadIdx.x & 63;
    int n = m & 63, w = (m >> 6) & 511, b = m >> 15;
    int ih = n >> 4, iw = (n >> 2) & 3, it = n & 3;
    int wh = w >> 6, ww = (w >> 3) & 7, wt = w & 7;
    int h  = (wh * 4 + ih + shift) & 31;
    int w2 = (ww * 4 + iw + shift) & 31;
    int t  = (wt * 4 + it + shift) & 31;
    size_t tok = ((size_t)b << 15) + ((h * 32 + w2) * 32 + t);
    const float* xp = x + tok * 128;
    float v0 = xp[lane], v1 = xp[lane + 64];
    float s = v0 + v1, sq = v0 * v0 + v1 * v1;
    #pragma unroll
    for (int o = 32; o > 0; o >>= 1) { s += __shfl_xor(s, o); sq += __shfl_xor(sq, o); }
    float mu  = s * (1.0f / 128.0f);
    float var = sq * (1.0f / 128.0f) - mu * mu;
    float rs  = rsqrtf(var + 1e-5f);
    bf16* op = out + (size_t)m * 128;
    op[lane]      = __float2bfloat16((v0 - mu) * rs * g[lane]      + bta[lane]);
    op[lane + 64] = __float2bfloat16((v1 - mu) * rs * g[lane + 64] + bta[lane + 64]);
}

// ---------------------------------------------------------------------------
// bf16 MFMA GEMM with coalesced LDS-staged epilogues. (unchanged from R6)
// ---------------------------------------------------------------------------
__global__ __launch_bounds__(256) void gemm_bf16_kernel(
    const bf16* __restrict__ A, const bf16* __restrict__ Bw,
    const float* __restrict__ bias, bf16* __restrict__ Cb, float* __restrict__ Cf,
    float* __restrict__ aux, const float* __restrict__ p1, const float* __restrict__ p2,
    int M, int N, int K, int mode, int shift)
{
    __shared__ __align__(16) char smem[34816];
    __shared__ float cs[128];
    __shared__ float cq[128];
    short* As = (short*)smem;
    short* Bs = (short*)(smem + 8192);
    int tid = threadIdx.x;
    int lane = tid & 63, wv = tid >> 6;
    int wm = wv >> 1, wn = wv & 1;
    int ln15 = lane & 15, quad = lane >> 4;
    int q8 = quad * 8;
    int nBase = blockIdx.x * 128;
    int mBase = blockIdx.y * 128;
    floatx4 acc[4][4] = {};

    if (mode == 4 && tid < 128) { cs[tid] = 0.f; cq[tid] = 0.f; }

    int srow = tid >> 2, scb = tid & 3;
    for (int k0 = 0; k0 < K; k0 += 32) {
        #pragma unroll
        for (int i = 0; i < 2; ++i) {
            int row = srow + i * 64;
            ((uint4*)As)[i * 256 + tid] =
                *(const uint4*)(A + (size_t)(mBase + row) * K + k0 + scb * 8);
            ((uint4*)Bs)[i * 256 + tid] =
                *(const uint4*)(Bw + (size_t)(nBase + row) * K + k0 + scb * 8);
        }
        __syncthreads();
        short8 af[4], bfr[4];
        #pragma unroll
        for (int mt = 0; mt < 4; ++mt)
            af[mt] = *(const short8*)&As[(wm * 64 + mt * 16 + ln15) * 32 + q8];
        #pragma unroll
        for (int nt = 0; nt < 4; ++nt)
            bfr[nt] = *(const short8*)&Bs[(wn * 64 + nt * 16 + ln15) * 32 + q8];
        #pragma unroll
        for (int mt = 0; mt < 4; ++mt)
            #pragma unroll
            for (int nt = 0; nt < 4; ++nt)
                acc[mt][nt] = __builtin_amdgcn_mfma_f32_16x16x32_bf16(
                    af[mt], bfr[nt], acc[mt][nt], 0, 0, 0);
        __syncthreads();
    }

    if (mode == 4) {
        #pragma unroll
        for (int nt = 0; nt < 4; ++nt) {
            int nl = wn * 64 + nt * 16 + ln15;
            float bs = bias[nBase + nl];
            float s = 0.f, sq = 0.f;
            #pragma unroll
            for (int mt = 0; mt < 4; ++mt)
                #pragma unroll
                for (int r = 0; r < 4; ++r) {
                    float v = acc[mt][nt][r] + bs;
                    s += v; sq += v * v;
                }
            atomicAdd(&cs[nl], s);
            atomicAdd(&cq[nl], sq);
        }
        __syncthreads();
        if (tid < 128) {
            atomicAdd(&aux[nBase + tid], cs[tid]);
            atomicAdd(&aux[256 + nBase + tid], cq[tid]);
        }
        return;
    }

    if (mode == 0) {
        bf16* estage = (bf16*)smem;          // [128][136]
        #pragma unroll
        for (int mt = 0; mt < 4; ++mt)
            #pragma unroll
            for (int nt = 0; nt < 4; ++nt)
                #pragma unroll
                for (int r = 0; r < 4; ++r) {
                    int row = wm * 64 + mt * 16 + quad * 4 + r;
                    int col = wn * 64 + nt * 16 + ln15;
                    estage[row * 136 + col] =
                        __float2bfloat16(acc[mt][nt][r] + bias[nBase + col]);
                }
        __syncthreads();
        int row = tid >> 1, hf = tid & 1;
        #pragma unroll
        for (int j = 0; j < 4; ++j) {
            int col = hf * 64 + j * 16;
            *(uint4*)(Cb + (size_t)(mBase + row) * N + nBase + col) =
                *(const uint4*)&estage[row * 136 + col];
            *(uint4*)(Cb + (size_t)(mBase + row) * N + nBase + col + 8) =
                *(const uint4*)&estage[row * 136 + col + 8];
        }
        return;
    }

    if (mode == 2) {
        float* fstage = (float*)smem;        // [64][132]
        #pragma unroll
        for (int hf = 0; hf < 2; ++hf) {
            if (wm == hf) {
                #pragma unroll
                for (int mt = 0; mt < 4; ++mt)
                    #pragma unroll
                    for (int nt = 0; nt < 4; ++nt)
                        #pragma unroll
                        for (int r = 0; r < 4; ++r) {
                            int ml = mt * 16 + quad * 4 + r;
                            int col = wn * 64 + nt * 16 + ln15;
                            fstage[ml * 132 + col] = acc[mt][nt][r] + bias[col];
                        }
            }
            __syncthreads();
            int tl = tid >> 2, part = tid & 3;
            int g = mBase + hf * 64 + tl;
            int n_ = g & 63, w = (g >> 6) & 511, b = g >> 15;
            int ih = n_ >> 4, iw = (n_ >> 2) & 3, it = n_ & 3;
            int wh = w >> 6, ww = (w >> 3) & 7, wt = w & 7;
            int h  = (wh * 4 + ih + shift) & 31;
            int w2 = (ww * 4 + iw + shift) & 31;
            int t  = (wt * 4 + it + shift) & 31;
            size_t tok = ((size_t)b << 15) + ((h * 32 + w2) * 32 + t);
            float* dst = aux + tok * 128 + part * 32;
            #pragma unroll
            for (int j = 0; j < 8; ++j) {
                float4 a = *(float4*)(dst + j * 4);
                float4 l = *(const float4*)&fstage[tl * 132 + part * 32 + j * 4];
                a.x += l.x; a.y += l.y; a.z += l.z; a.w += l.w;
                *(float4*)(dst + j * 4) = a;
            }
            __syncthreads();
        }
        return;
    }

    // mode 5: BN + ReLU + transposed store
    {
        float* fstage = (float*)smem;        // [64 nn][132 sp]
        int b = mBase >> 15, sp0 = mBase & 32767;
        #pragma unroll
        for (int hf = 0; hf < 2; ++hf) {
            if (wn == hf) {
                #pragma unroll
                for (int nt = 0; nt < 4; ++nt) {
                    int ncol = nt * 16 + ln15;
                    int nn = nBase + hf * 64 + ncol;
                    float mean = aux[nn] * (1.0f / 65536.0f);
                    float var  = aux[256 + nn] * (1.0f / 65536.0f) - mean * mean;
                    float sc = rsqrtf(var + 1e-5f) * p1[nn];
                    float off = p2[nn] + bias[nn] * sc - mean * sc;
                    #pragma unroll
                    for (int mt = 0; mt < 4; ++mt)
                        #pragma unroll
                        for (int r = 0; r < 4; ++r) {
                            int ml = wm * 64 + mt * 16 + quad * 4 + r;
                            float y = acc[mt][nt][r] * sc + off;
                            fstage[ncol * 132 + ml] = fmaxf(y, 0.f);
                        }
                }
            }
            __syncthreads();
            int nl = tid >> 2, part = tid & 3;
            int nn = nBase + hf * 64 + nl;
            float* dst = Cf + (((size_t)(b * 256 + nn)) << 15) + sp0 + part * 32;
            #pragma unroll
            for (int j = 0; j < 8; ++j)
                *(float4*)(dst + j * 4) = *(const float4*)&fstage[nl * 132 + part * 32 + j * 4];
            __syncthreads();
        }
    }
}

// ---------------------------------------------------------------------------
// Fused MLP v3: LN2 + fc1 + GELU + fc2 + residual. 64 tokens/block, 1024 blks.
// Hidden computed in two 256-col chunks (hid LDS halved); fc2 accumulates
// across chunks. Weights read from MFMA-fragment-packed pw1/pw2 (coalesced
// 1 KB/wave-step). LDS 50 KB -> 3 blocks/CU.
// ---------------------------------------------------------------------------
__global__ __launch_bounds__(256) void mlp_kernel(
    float* __restrict__ xbuf, const float* __restrict__ g, const float* __restrict__ bta,
    const bf16* __restrict__ pw1, const float* __restrict__ b1,
    const bf16* __restrict__ pw2, const float* __restrict__ b2,
    bf16* __restrict__ xout16)
{
    __shared__ __align__(16) bf16 aln[64 * 136];     // 17.4 KB
    __shared__ __align__(16) bf16 hidc[64 * 264];    // 33.0 KB (also ostage [64][132] f32)
    float* ostage = (float*)hidc;
    int tid = threadIdx.x;
    int lane = tid & 63, wv = tid >> 6;
    int ln15 = lane & 15, quad = lane >> 4;
    int q8 = quad * 8;
    size_t tok0 = (size_t)blockIdx.x * 64;

    // LayerNorm: wave wv handles tokens wv*16 .. +15
    #pragma unroll
    for (int itk = 0; itk < 16; ++itk) {
        int t = wv * 16 + itk;
        const float* xp = xbuf + (tok0 + t) * 128;
        float v0 = xp[lane], v1 = xp[lane + 64];
        float s = v0 + v1, sq = v0 * v0 + v1 * v1;
        #pragma unroll
        for (int o = 32; o > 0; o >>= 1) { s += __shfl_xor(s, o); sq += __shfl_xor(sq, o); }
        float mu  = s * (1.0f / 128.0f);
        float var = sq * (1.0f / 128.0f) - mu * mu;
        float rs  = rsqrtf(var + 1e-5f);
        aln[t * 136 + lane]      = __float2bfloat16((v0 - mu) * rs * g[lane]      + bta[lane]);
        aln[t * 136 + lane + 64] = __float2bfloat16((v1 - mu) * rs * g[lane + 64] + bta[lane + 64]);
    }
    __syncthreads();

    floatx4 acc2[4][2] = {};                          // fc2 accumulators (persist)
    #pragma unroll
    for (int cc = 0; cc < 2; ++cc) {
        // fc1 chunk: wave wv computes hidden cols [cc*256 + wv*64, +64)
        floatx4 acc[4][4] = {};
        const bf16* p1w = pw1 + (size_t)(cc * 4 + wv) * 8192;
        #pragma unroll
        for (int kk = 0; kk < 4; ++kk) {
            short8 af[4], bfr[4];
            #pragma unroll
            for (int mt = 0; mt < 4; ++mt)
                af[mt] = *(const short8*)&aln[(mt * 16 + ln15) * 136 + kk * 32 + q8];
            #pragma unroll
            for (int nt = 0; nt < 4; ++nt)
                bfr[nt] = *(const short8*)(p1w + kk * 2048 + nt * 512 + lane * 8);
            #pragma unroll
            for (int mt = 0; mt < 4; ++mt)
                #pragma unroll
                for (int nt = 0; nt < 4; ++nt)
                    acc[mt][nt] = __builtin_amdgcn_mfma_f32_16x16x32_bf16(
                        af[mt], bfr[nt], acc[mt][nt], 0, 0, 0);
        }
        if (cc) __syncthreads();   // protect hidc until all fc2 reads of prev chunk done
        #pragma unroll
        for (int mt = 0; mt < 4; ++mt)
            #pragma unroll
            for (int nt = 0; nt < 4; ++nt)
                #pragma unroll
                for (int r = 0; r < 4; ++r) {
                    int m = mt * 16 + quad * 4 + r;
                    int ncl = wv * 64 + nt * 16 + ln15;
                    float v = acc[mt][nt][r] + b1[cc * 256 + ncl];
                    v = 0.5f * v * (1.0f + erff(v * 0.70710678118654752f));
                    hidc[m * 264 + ncl] = __float2bfloat16(v);
                }
        __syncthreads();
        // fc2 partial over this chunk's K=256; wave wv -> out cols wv*32..+31
        const bf16* p2w = pw2 + (size_t)(wv * 2 + cc) * 8192;
        #pragma unroll
        for (int ks = 0; ks < 8; ++ks) {
            short8 af[4], bfr[2];
            #pragma unroll
            for (int mt = 0; mt < 4; ++mt)
                af[mt] = *(const short8*)&hidc[(mt * 16 + ln15) * 264 + ks * 32 + q8];
            #pragma unroll
            for (int nt = 0; nt < 2; ++nt)
                bfr[nt] = *(const short8*)(p2w + ks * 1024 + nt * 512 + lane * 8);
            #pragma unroll
            for (int mt = 0; mt < 4; ++mt)
                #pragma unroll
                for (int nt = 0; nt < 2; ++nt)
                    acc2[mt][nt] = __builtin_amdgcn_mfma_f32_16x16x32_bf16(
                        af[mt], bfr[nt], acc2[mt][nt], 0, 0, 0);
        }
    }
    __syncthreads();   // all fc2 reads done; reuse hidc region as ostage

    #pragma unroll
    for (int mt = 0; mt < 4; ++mt)
        #pragma unroll
        for (int nt = 0; nt < 2; ++nt)
            #pragma unroll
            for (int r = 0; r < 4; ++r) {
                int m = mt * 16 + quad * 4 + r;
                int n = wv * 32 + nt * 16 + ln15;
                ostage[m * 132 + n] = acc2[mt][nt][r] + b2[n];
            }
    __syncthreads();

    // residual: coalesced float4
    #pragma unroll
    for (int jj = 0; jj < 8; ++jj) {
        int idx = (jj * 256 + tid) * 4;          // 0..8191 floats
        int t = idx >> 7, c = idx & 127;
        float4 v = *(const float4*)(xbuf + tok0 * 128 + idx);
        float4 o = *(const float4*)&ostage[t * 132 + c];
        v.x += o.x; v.y += o.y; v.z += o.z; v.w += o.w;
        *(float4*)(xbuf + tok0 * 128 + idx) = v;
        if (xout16) {
            __align__(8) bf16 hh[4];
            hh[0] = __float2bfloat16(v.x); hh[1] = __float2bfloat16(v.y);
            hh[2] = __float2bfloat16(v.z); hh[3] = __float2bfloat16(v.w);
            *(uint2*)(xout16 + tok0 * 128 + idx) = *(const uint2*)hh;
        }
    }
}

// ---------------------------------------------------------------------------
// Windowed attention: vectorized 16B q/k/v loads, head-major rpbt.
// rpbt arg pre-offset to layer: [head][343].
// ---------------------------------------------------------------------------
__global__ __launch_bounds__(64) void attn_kernel(
    const bf16* __restrict__ qkv, const float* __restrict__ rpbt,
    bf16* __restrict__ outp, int shift)
{
    __shared__ float kt[64][16];
    __shared__ float vt[64][16];
    __shared__ float rp[343];
    __shared__ int   cnt[64];
    int blk = blockIdx.x;
    int head = blk & 7;
    int lw = blk >> 3;
    int i = threadIdx.x;
    const short8* sp = (const short8*)(qkv + (size_t)(lw * 64 + i) * 384 + head * 16);
    short8 q0 = sp[0], q1 = sp[1];
    short8 k0 = sp[16], k1 = sp[17];
    short8 v0 = sp[32], v1 = sp[33];
    float q[16];
    #pragma unroll
    for (int d = 0; d < 8; ++d) {
        q[d] = b2f(q0[d]) * 0.25f;  q[d + 8] = b2f(q1[d]) * 0.25f;
        kt[i][d] = b2f(k0[d]);      kt[i][d + 8] = b2f(k1[d]);
        vt[i][d] = b2f(v0[d]);      vt[i][d + 8] = b2f(v1[d]);
    }
    for (int j = i; j < 343; j += 64) rp[j] = rpbt[head * 343 + j];
    int w = lw & 511;
    int ih = i >> 4, iw = (i >> 2) & 3, it = i & 3;
    if (shift) {
        int wh = w >> 6, ww = (w >> 3) & 7, wt = w & 7;
        int h = wh * 4 + ih, w2 = ww * 4 + iw, t = wt * 4 + it;
        int rh = (h  < 28) ? 0 : ((h  < 30) ? 1 : 2);
        int rw = (w2 < 28) ? 0 : ((w2 < 30) ? 1 : 2);
        int rt = (t  < 28) ? 0 : ((t  < 30) ? 1 : 2);
        cnt[i] = (rh * 3 + rw) * 3 + rt;
    }
    __syncthreads();
    float logits[64];
    int ci = shift ? cnt[i] : 0;
    #pragma unroll
    for (int j = 0; j < 64; ++j) {
        float d0 = 0.f;
        #pragma unroll
        for (int d = 0; d < 16; ++d) d0 += q[d] * kt[j][d];
        int jh = j >> 4, jw = (j >> 2) & 3, jt = j & 3;
        int ridx = ((ih - jh + 3) * 7 + (iw - jw + 3)) * 7 + (it - jt + 3);
        d0 += rp[ridx];
        if (shift && cnt[j] != ci) d0 -= 100.0f;
        logits[j] = d0;
    }
    float mx = -1e30f;
    #pragma unroll
    for (int j = 0; j < 64; ++j) mx = fmaxf(mx, logits[j]);
    float ssum = 0.f;
    #pragma unroll
    for (int j = 0; j < 64; ++j) { float e = __expf(logits[j] - mx); logits[j] = e; ssum += e; }
    float inv = 1.0f / ssum;
    float o[16] = {};
    #pragma unroll
    for (int j = 0; j < 64; ++j) {
        float p = logits[j] * inv;
        #pragma unroll
        for (int d = 0; d < 16; ++d) o[d] += p * vt[j][d];
    }
    bf16* op = outp + (size_t)(lw * 64 + i) * 128 + head * 16;
    #pragma unroll
    for (int d = 0; d < 16; ++d) op[d] = __float2bfloat16(o[d]);
}

// ---------------------------------------------------------------------------
// Depthwise 3x3x3 conv, bf16 in/out, register t-window reuse.
// ---------------------------------------------------------------------------
__global__ __launch_bounds__(512) void dwconv_kernel(
    const bf16* __restrict__ x, const float* __restrict__ dwt,
    const float* __restrict__ bias, bf16* __restrict__ out)
{
    int blk = blockIdx.x;
    int b = blk >> 10;
    int h = (blk >> 5) & 31;
    int w = blk & 31;
    int tid = threadIdx.x;
    int c = tid & 127;
    int t0 = (tid >> 7) * 8;
    float acc[8];
    float bs = bias[c];
    #pragma unroll
    for (int o = 0; o < 8; ++o) acc[o] = bs;
    #pragma unroll
    for (int kh = 0; kh < 3; ++kh) {
        int hh = h + kh - 1;
        if (hh < 0 || hh > 31) continue;
        #pragma unroll
        for (int kw = 0; kw < 3; ++kw) {
            int ww = w + kw - 1;
            if (ww < 0 || ww > 31) continue;
            const bf16* px = x + (((size_t)(b << 15) + (hh * 32 + ww) * 32) * 128) + c;
            float v[10];
            #pragma unroll
            for (int u = 0; u < 10; ++u) {
                int tt = t0 - 1 + u;
                v[u] = (tt >= 0 && tt < 32) ? __bfloat162float(px[(size_t)tt * 128]) : 0.f;
            }
            float w0 = dwt[((kh * 3 + kw) * 3 + 0) * 128 + c];
            float w1 = dwt[((kh * 3 + kw) * 3 + 1) * 128 + c];
            float w2 = dwt[((kh * 3 + kw) * 3 + 2) * 128 + c];
            #pragma unroll
            for (int o = 0; o < 8; ++o)
                acc[o] += v[o] * w0 + v[o + 1] * w1 + v[o + 2] * w2;
        }
    }
    bf16* po = out + (((size_t)(b << 15) + (h * 32 + w) * 32 + t0) * 128) + c;
    #pragma unroll
    for (int o = 0; o < 8; ++o) po[(size_t)o * 128] = __float2bfloat16(acc[o]);
}

// ---------------------------------------------------------------------------
extern "C" void kernel_launch(void* const* d_in, const int* in_sizes, int n_in,
                              void* d_out, int out_size, void* d_ws, size_t ws_size,
                              hipStream_t stream)
{
    const float* x_in    = (const float*)d_in[0];
    const float* norm1_g = (const float*)d_in[1];
    const float* norm1_b = (const float*)d_in[2];
    const float* qkv_w   = (const float*)d_in[3];
    const float* qkv_b   = (const float*)d_in[4];
    const float* proj_w  = (const float*)d_in[5];
    const float* proj_b  = (const float*)d_in[6];
    const float* rpb     = (const float*)d_in[7];
    const float* norm2_g = (const float*)d_in[8];
    const float* norm2_b = (const float*)d_in[9];
    const float* fc1_w   = (const float*)d_in[10];
    const float* fc1_b   = (const float*)d_in[11];
    const float* fc2_w   = (const float*)d_in[12];
    const float* fc2_b   = (const float*)d_in[13];
    const float* dw_w    = (const float*)d_in[14];
    const float* dw_b    = (const float*)d_in[15];
    const float* pw_w    = (const float*)d_in[16];
    const float* pw_b    = (const float*)d_in[17];
    const float* bn_g    = (const float*)d_in[18];
    const float* bn_b    = (const float*)d_in[19];
    float* out = (float*)d_out;

    char* ws = (char*)d_ws;
    float* xbuf   = (float*)ws;                          // [0,32MB)   fp32 [TOK,128]
    bf16*  wbf    = (bf16*)(ws + 33554432ULL);           // [32,34MB)  bf16 weights
    float* dwt    = (float*)(ws + 35651584ULL);          // 27x128 fp32
    float* stats  = (float*)(ws + 35717120ULL);          // 2 KB
    bf16*  pw1    = (bf16*)(ws + 35782656ULL);           // 512 KB packed fc1
    bf16*  pw2    = (bf16*)(ws + 36306944ULL);           // 512 KB packed fc2
    float* rpbt   = (float*)(ws + 36831232ULL);          // 44 KB
    bf16*  lnbuf  = (bf16*)(ws + 37748736ULL);           // [36,52MB)  [TOK,128]
    bf16*  attnbuf= (bf16*)(ws + 54525952ULL);           // [52,68MB)  [TOK,128]
    bf16*  qkvbuf = (bf16*)(ws + 71303168ULL);           // [68,116MB) [TOK,384]
    bf16*  dwbuf  = attnbuf;
    bf16*  dcbuf  = lnbuf;

    bf16* wqkv  = wbf;                 // 4 x 384 x 128
    bf16* wproj = wbf + 196608;        // 4 x 128 x 128
    bf16* wpw   = wbf + 786432;        // 256 x 128

    hipLaunchKernelGGL(prep_kernel, dim3(3200), dim3(256), 0, stream,
                       qkv_w, proj_w, fc1_w, fc2_w, pw_w, dw_w, wbf, dwt, stats);
    hipLaunchKernelGGL(pack_kernel, dim3(2048), dim3(256), 0, stream,
                       fc1_w, fc2_w, rpb, pw1, pw2, rpbt);
    hipLaunchKernelGGL(transpose_in_kernel, dim3(1024), dim3(256), 0, stream, x_in, xbuf);

    const int shifts[4] = {0, 2, 0, 2};
    for (int i = 0; i < 4; ++i) {
        int s = shifts[i];
        // --- attention half ---
        hipLaunchKernelGGL(ln_window_kernel, dim3(TOK / 4), dim3(256), 0, stream,
                           xbuf, lnbuf, norm1_g + i * 128, norm1_b + i * 128, s);
        hipLaunchKernelGGL(gemm_bf16_kernel, dim3(3, TOK / 128), dim3(256), 0, stream,
                           lnbuf, wqkv + (size_t)i * 49152, qkv_b + i * 384,
                           qkvbuf, (float*)nullptr, (float*)nullptr,
                           (const float*)nullptr, (const float*)nullptr,
                           TOK, 384, 128, 0, 0);
        hipLaunchKernelGGL(attn_kernel, dim3(1024 * HEADS), dim3(64), 0, stream,
                           qkvbuf, rpbt + i * 2744, attnbuf, s);
        hipLaunchKernelGGL(gemm_bf16_kernel, dim3(1, TOK / 128), dim3(256), 0, stream,
                           attnbuf, wproj + (size_t)i * 16384, proj_b + i * 128,
                           (bf16*)nullptr, (float*)nullptr, xbuf,
                           (const float*)nullptr, (const float*)nullptr,
                           TOK, 128, 128, 2, s);
        // --- fused MLP (64-token blocks, packed weights) ---
        hipLaunchKernelGGL(mlp_kernel, dim3(TOK / 64), dim3(256), 0, stream,
                           xbuf, norm2_g + i * 128, norm2_b + i * 128,
                           pw1 + (size_t)i * 65536, fc1_b + i * 512,
                           pw2 + (size_t)i * 65536, fc2_b + i * 128,
                           (i == 3) ? dwbuf : (bf16*)nullptr);
    }

    // connectBlock
    hipLaunchKernelGGL(dwconv_kernel, dim3(2048), dim3(512), 0, stream,
                       dwbuf, dwt, dw_b, dcbuf);
    hipLaunchKernelGGL(gemm_bf16_kernel, dim3(OUTC / 128, TOK / 128), dim3(256), 0, stream,
                       dcbuf, wpw, pw_b,
                       (bf16*)nullptr, (float*)nullptr, stats,
                       (const float*)nullptr, (const float*)nullptr,
                       TOK, OUTC, 128, 4, 0);
    hipLaunchKernelGGL(gemm_bf16_kernel, dim3(OUTC / 128, TOK / 128), dim3(256), 0, stream,
                       dcbuf, wpw, pw_b,
                       (bf16*)nullptr, out, stats,
                       bn_g, bn_b,
                       TOK, OUTC, 128, 5, 0);
}